// Round 8
// baseline (1453.219 us; speedup 1.0000x reference)
//
#include <hip/hip_runtime.h>
#include <hip/hip_bf16.h>
#include <hip/hip_cooperative_groups.h>
#include <math.h>

namespace cg = cooperative_groups;

// ---------------------------------------------------------------------------
// GMVAE fused pipeline. Round 8: cooperative EM mega-kernel (zgen + init +
// 5x(E,M) + KL in ONE dispatch, grid-synced), merged conversion kernel.
// 30 dispatches -> 11. Numerics identical to round 7 (absmax 0).
// ---------------------------------------------------------------------------

#define BATCH 16
#define SEQ 256
#define DIM 512
#define NH 4
#define DH 128
#define LD 64
#define KC 20
#define MC 10
#define NPTS 2560
#define BS_TOT 4096
#define NROWS 40960
#define LOG_NORM (-0.9189385332046727f)

typedef __attribute__((ext_vector_type(8))) short bf16x8;
typedef __attribute__((ext_vector_type(4))) float f32x4;
typedef __hip_bfloat16 bf;

__device__ inline float warpReduceSum(float v) {
    for (int o = 32; o > 0; o >>= 1) v += __shfl_down(v, o);
    return v;
}

__device__ inline void async_copy16(const bf* g, bf* l) {
    __builtin_amdgcn_global_load_lds(
        (const __attribute__((address_space(1))) unsigned int*)g,
        (__attribute__((address_space(3))) unsigned int*)l, 16, 0, 0);
}

__device__ inline void split_store(float x, bf* ph, bf* pl, long idx) {
    const bf h = __float2bfloat16(x);
    ph[idx] = h;
    pl[idx] = __float2bfloat16(x - __bfloat162float(h));
}

// ---------------------------------------------------------------------------
// Split-bf16 MFMA GEMM, 64x128 tile, BK=32 (verified round 6/7).
// MODE: 0=QKV(fused q/k/vT out) 3=OPROJ(bias,relu,+resid) 4=STATS(fp32+bias)
// ---------------------------------------------------------------------------
template<int MODE>
__global__ __launch_bounds__(256, 3)
void gemm3t(const bf* __restrict__ Ah, const bf* __restrict__ Al,
            const bf* __restrict__ Bh, const bf* __restrict__ Bl,
            int K, int lda, int ldb,
            const float* __restrict__ b0, const float* __restrict__ b1v,
            const float* __restrict__ b2v,
            float* __restrict__ outF,
            bf* __restrict__ P1h, bf* __restrict__ P1l,
            bf* __restrict__ P2h, bf* __restrict__ P2l,
            bf* __restrict__ P3h, bf* __restrict__ P3l,
            const bf* __restrict__ Rh, const bf* __restrict__ Rl)
{
    __shared__ __align__(16) char smem[24576];
    bf* Ash = (bf*)smem;
    bf* Asl = (bf*)(smem + 4096);
    bf* Bsh = (bf*)(smem + 8192);
    bf* Bsl = (bf*)(smem + 16384);
    float* Xs = (float*)smem;        // epilogue overlay [64][68]

    const int t = threadIdx.x;
    const int m0 = blockIdx.y * 64, n0 = blockIdx.x * 128;
    const int w = t >> 6, lane = t & 63;
    const int wn = w * 32;
    const int fm = lane & 15, quad = lane >> 4, fk = quad * 8;
    const int srow = t >> 2, scol = (t & 3) * 8;

    f32x4 acc[4][2];
#pragma unroll
    for (int i = 0; i < 4; i++)
#pragma unroll
        for (int j = 0; j < 2; j++) acc[i][j] = (f32x4){0.f, 0.f, 0.f, 0.f};

    const int nk = K >> 5;
    for (int kk = 0; kk < nk; kk++) {
        const long ao = (long)(m0 + srow) * lda + kk * 32 + scol;
        const long bo = (long)(n0 + srow) * ldb + kk * 32 + scol;
        async_copy16(Ah + ao, Ash + w * 512);
        async_copy16(Al + ao, Asl + w * 512);
        async_copy16(Bh + bo, Bsh + w * 512);
        async_copy16(Bh + bo + 64L * ldb, Bsh + 2048 + w * 512);
        async_copy16(Bl + bo, Bsl + w * 512);
        async_copy16(Bl + bo + 64L * ldb, Bsl + 2048 + w * 512);
        __syncthreads();

        bf16x8 afh[4], afl[4], bfh[2], bfl[2];
#pragma unroll
        for (int mi = 0; mi < 4; mi++) {
            afh[mi] = *(const bf16x8*)&Ash[(mi * 16 + fm) * 32 + fk];
            afl[mi] = *(const bf16x8*)&Asl[(mi * 16 + fm) * 32 + fk];
        }
#pragma unroll
        for (int ni = 0; ni < 2; ni++) {
            bfh[ni] = *(const bf16x8*)&Bsh[(wn + ni * 16 + fm) * 32 + fk];
            bfl[ni] = *(const bf16x8*)&Bsl[(wn + ni * 16 + fm) * 32 + fk];
        }
#pragma unroll
        for (int mi = 0; mi < 4; mi++)
#pragma unroll
            for (int ni = 0; ni < 2; ni++) {
                acc[mi][ni] = __builtin_amdgcn_mfma_f32_16x16x32_bf16(
                    afh[mi], bfh[ni], acc[mi][ni], 0, 0, 0);
                acc[mi][ni] = __builtin_amdgcn_mfma_f32_16x16x32_bf16(
                    afh[mi], bfl[ni], acc[mi][ni], 0, 0, 0);
                acc[mi][ni] = __builtin_amdgcn_mfma_f32_16x16x32_bf16(
                    afl[mi], bfh[ni], acc[mi][ni], 0, 0, 0);
            }
        __syncthreads();
    }

    const int rl = t >> 2;
    const int cc4 = (t & 3) * 16;

    for (int p = 0; p < 2; p++) {
        if ((w >> 1) == p) {
            const int cb = wn - p * 64;
#pragma unroll
            for (int mi = 0; mi < 4; mi++)
#pragma unroll
                for (int ni = 0; ni < 2; ni++) {
                    const int c = cb + ni * 16 + fm;
#pragma unroll
                    for (int r = 0; r < 4; r++)
                        Xs[(mi * 16 + quad * 4 + r) * 68 + c] = acc[mi][ni][r];
                }
        }
        __syncthreads();

        if (MODE == 0 && n0 >= 1024) {
            const int hh = (n0 >> 7) & 3;
            const int dd = p * 64 + rl;
            const int bb = m0 >> 8;
            const int sb = (m0 & 255) + cc4;
            const float bias = b2v[hh * 128 + dd];
            const long ob = (((long)(bb * NH + hh) * DH + dd) << 8) + sb;
#pragma unroll
            for (int j = 0; j < 2; j++) {
                bf16x8 vh, vl;
#pragma unroll
                for (int i = 0; i < 8; i++) {
                    const float x = Xs[(cc4 + j * 8 + i) * 68 + rl] + bias;
                    const bf h = __float2bfloat16(x);
                    vh[i] = *(const short*)&h;
                    const bf l = __float2bfloat16(x - __bfloat162float(h));
                    vl[i] = *(const short*)&l;
                }
                *(bf16x8*)&P3h[ob + j * 8] = vh;
                *(bf16x8*)&P3l[ob + j * 8] = vl;
            }
        } else {
            float xv[16];
#pragma unroll
            for (int i = 0; i < 4; i++)
                *(float4*)&xv[i * 4] = *(const float4*)&Xs[rl * 68 + cc4 + i * 4];

            if (MODE == 0) {
                const int which = n0 >> 9;
                const int colq = (n0 & 511) + p * 64 + cc4;
                const float* bias = which ? b1v : b0;
                bf* Ph = which ? P2h : P1h;
                bf* Pl = which ? P2l : P1l;
                const long ob = (long)(m0 + rl) * 512 + colq;
#pragma unroll
                for (int j = 0; j < 2; j++) {
                    bf16x8 vh, vl;
#pragma unroll
                    for (int i = 0; i < 8; i++) {
                        const float x = xv[j * 8 + i] + bias[colq + j * 8 + i];
                        const bf h = __float2bfloat16(x); vh[i] = *(const short*)&h;
                        const bf l = __float2bfloat16(x - __bfloat162float(h));
                        vl[i] = *(const short*)&l;
                    }
                    *(bf16x8*)&Ph[ob + j * 8] = vh;
                    *(bf16x8*)&Pl[ob + j * 8] = vl;
                }
            } else if (MODE == 3) {
                const int colg = n0 + p * 64 + cc4;
                const long ob = (long)(m0 + rl) * 512 + colg;
#pragma unroll
                for (int j = 0; j < 2; j++) {
                    const bf16x8 rh = *(const bf16x8*)&Rh[ob + j * 8];
                    const bf16x8 rv = *(const bf16x8*)&Rl[ob + j * 8];
                    bf16x8 vh, vl;
#pragma unroll
                    for (int i = 0; i < 8; i++) {
                        short sh = rh[i], sl = rv[i];
                        float x = fmaxf(xv[j * 8 + i] + b0[colg + j * 8 + i], 0.f)
                                + __bfloat162float(*(const bf*)&sh)
                                + __bfloat162float(*(const bf*)&sl);
                        const bf h = __float2bfloat16(x); vh[i] = *(const short*)&h;
                        const bf l = __float2bfloat16(x - __bfloat162float(h));
                        vl[i] = *(const short*)&l;
                    }
                    *(bf16x8*)&P1h[ob + j * 8] = vh;
                    *(bf16x8*)&P1l[ob + j * 8] = vl;
                }
            } else {
                const int colg = p * 64 + cc4;
                const long ob = (long)(m0 + rl) * 128 + colg;
#pragma unroll
                for (int i = 0; i < 4; i++) {
                    float4 v = *(float4*)&xv[i * 4];
                    v.x += b0[colg + i * 4 + 0];
                    v.y += b0[colg + i * 4 + 1];
                    v.z += b0[colg + i * 4 + 2];
                    v.w += b0[colg + i * 4 + 3];
                    *(float4*)&outF[ob + i * 4] = v;
                }
            }
        }
        __syncthreads();
    }
}

// ---------------------------------------------------------------------------
// Fused attention (unchanged, verified).
// ---------------------------------------------------------------------------
__global__ __launch_bounds__(256)
void attn_fused(const bf* __restrict__ qh, const bf* __restrict__ ql,
                const bf* __restrict__ kh, const bf* __restrict__ kl,
                const bf* __restrict__ vTh, const bf* __restrict__ vTl,
                bf* __restrict__ oh, bf* __restrict__ ol)
{
    __shared__ __align__(16) char smem[43008];
    bf* Qsh = (bf*)smem;            bf* Qsl = (bf*)(smem + 4096);
    bf* Ksh = (bf*)(smem + 8192);   bf* Ksl = (bf*)(smem + 24576);
    bf* Psh = (bf*)smem;            bf* Psl = (bf*)(smem + 4096);
    bf* Vsh = (bf*)(smem + 8192);   bf* Vsl = (bf*)(smem + 16384);
    float (*red)[4]  = (float(*)[4])(smem + 40960);
    float (*red2)[4] = (float(*)[4])(smem + 41984);

    const int t = threadIdx.x;
    const int z = blockIdx.y;
    const int m0 = blockIdx.x * 64;
    const int bb = z >> 2, hh = z & 3;
    const long hOff = (long)bb * 131072 + (long)hh * 128;
    const long vOff = (long)z * 32768;

    const int w = t >> 6, lane = t & 63;
    const int fm = lane & 15;
    const int quad = lane >> 4;
    const int fk = quad * 8;
    const int srow = t >> 2, scol = (t & 3) * 8;

    f32x4 acc[4][4];
#pragma unroll
    for (int i = 0; i < 4; i++)
#pragma unroll
        for (int j = 0; j < 4; j++) acc[i][j] = (f32x4){0.f, 0.f, 0.f, 0.f};

    for (int kk = 0; kk < 4; kk++) {
        const long ao = hOff + (long)(m0 + srow) * 512 + kk * 32 + scol;
        const long bo = hOff + (long)srow * 512 + kk * 32 + scol;
        async_copy16(qh + ao, Qsh + w * 512);
        async_copy16(ql + ao, Qsl + w * 512);
#pragma unroll
        for (int j = 0; j < 4; j++) {
            async_copy16(kh + bo + (long)j * 64 * 512, Ksh + w * 512 + j * 2048);
            async_copy16(kl + bo + (long)j * 64 * 512, Ksl + w * 512 + j * 2048);
        }
        __syncthreads();

        bf16x8 afh[4], afl[4];
#pragma unroll
        for (int mi = 0; mi < 4; mi++) {
            afh[mi] = *(const bf16x8*)&Qsh[(mi * 16 + fm) * 32 + fk];
            afl[mi] = *(const bf16x8*)&Qsl[(mi * 16 + fm) * 32 + fk];
        }
#pragma unroll
        for (int ni = 0; ni < 4; ni++) {
            const bf16x8 bh = *(const bf16x8*)&Ksh[(w * 64 + ni * 16 + fm) * 32 + fk];
            const bf16x8 bl = *(const bf16x8*)&Ksl[(w * 64 + ni * 16 + fm) * 32 + fk];
#pragma unroll
            for (int mi = 0; mi < 4; mi++) {
                acc[mi][ni] = __builtin_amdgcn_mfma_f32_16x16x32_bf16(
                    afh[mi], bh, acc[mi][ni], 0, 0, 0);
                acc[mi][ni] = __builtin_amdgcn_mfma_f32_16x16x32_bf16(
                    afh[mi], bl, acc[mi][ni], 0, 0, 0);
                acc[mi][ni] = __builtin_amdgcn_mfma_f32_16x16x32_bf16(
                    afl[mi], bh, acc[mi][ni], 0, 0, 0);
            }
        }
        __syncthreads();
    }

    const float alpha = 0.044194173824159216f;
#pragma unroll
    for (int mi = 0; mi < 4; mi++)
#pragma unroll
        for (int r = 0; r < 4; r++) {
            float m = -1e30f;
#pragma unroll
            for (int ni = 0; ni < 4; ni++) m = fmaxf(m, acc[mi][ni][r]);
            for (int o = 8; o > 0; o >>= 1) m = fmaxf(m, __shfl_xor(m, o));
            if (fm == 0) red[mi * 16 + quad * 4 + r][w] = m;
        }
    __syncthreads();
    float invr[4][4];
#pragma unroll
    for (int mi = 0; mi < 4; mi++)
#pragma unroll
        for (int r = 0; r < 4; r++) {
            const int rowl = mi * 16 + quad * 4 + r;
            const float mx = fmaxf(fmaxf(red[rowl][0], red[rowl][1]),
                                   fmaxf(red[rowl][2], red[rowl][3]));
            float s = 0.f;
#pragma unroll
            for (int ni = 0; ni < 4; ni++) {
                const float e = __expf((acc[mi][ni][r] - mx) * alpha);
                acc[mi][ni][r] = e;
                s += e;
            }
            for (int o = 8; o > 0; o >>= 1) s += __shfl_xor(s, o);
            if (fm == 0) red2[rowl][w] = s;
        }
    __syncthreads();
#pragma unroll
    for (int mi = 0; mi < 4; mi++)
#pragma unroll
        for (int r = 0; r < 4; r++) {
            const int rowl = mi * 16 + quad * 4 + r;
            invr[mi][r] = 1.f / (red2[rowl][0] + red2[rowl][1] + red2[rowl][2] + red2[rowl][3]);
        }

    f32x4 acc2[4][2];
#pragma unroll
    for (int i = 0; i < 4; i++)
#pragma unroll
        for (int j = 0; j < 2; j++) acc2[i][j] = (f32x4){0.f, 0.f, 0.f, 0.f};

    for (int kc = 0; kc < 8; kc++) {
        if (w == (kc >> 1)) {
            const int nib = (kc & 1) * 2;
#pragma unroll
            for (int mi = 0; mi < 4; mi++)
#pragma unroll
                for (int r = 0; r < 4; r++) {
                    const int row = mi * 16 + quad * 4 + r;
#pragma unroll
                    for (int j = 0; j < 2; j++) {
                        const float p = acc[mi][nib + j][r] * invr[mi][r];
                        const int cc = j * 16 + fm;
                        const bf h = __float2bfloat16(p);
                        Psh[row * 32 + cc] = h;
                        Psl[row * 32 + cc] = __float2bfloat16(p - __bfloat162float(h));
                    }
                }
        }
        const long vo = vOff + (long)srow * 256 + kc * 32 + scol;
        async_copy16(vTh + vo, Vsh + w * 512);
        async_copy16(vTh + vo + 64L * 256, Vsh + w * 512 + 2048);
        async_copy16(vTl + vo, Vsl + w * 512);
        async_copy16(vTl + vo + 64L * 256, Vsl + w * 512 + 2048);
        __syncthreads();

        bf16x8 pfh[4], pfl[4];
#pragma unroll
        for (int mi = 0; mi < 4; mi++) {
            pfh[mi] = *(const bf16x8*)&Psh[(mi * 16 + fm) * 32 + fk];
            pfl[mi] = *(const bf16x8*)&Psl[(mi * 16 + fm) * 32 + fk];
        }
#pragma unroll
        for (int ni = 0; ni < 2; ni++) {
            const bf16x8 vh = *(const bf16x8*)&Vsh[(w * 32 + ni * 16 + fm) * 32 + fk];
            const bf16x8 vl = *(const bf16x8*)&Vsl[(w * 32 + ni * 16 + fm) * 32 + fk];
#pragma unroll
            for (int mi = 0; mi < 4; mi++) {
                acc2[mi][ni] = __builtin_amdgcn_mfma_f32_16x16x32_bf16(
                    pfh[mi], vh, acc2[mi][ni], 0, 0, 0);
                acc2[mi][ni] = __builtin_amdgcn_mfma_f32_16x16x32_bf16(
                    pfh[mi], vl, acc2[mi][ni], 0, 0, 0);
                acc2[mi][ni] = __builtin_amdgcn_mfma_f32_16x16x32_bf16(
                    pfl[mi], vh, acc2[mi][ni], 0, 0, 0);
            }
        }
        __syncthreads();
    }

#pragma unroll
    for (int ni = 0; ni < 2; ni++) {
        const int col = hh * 128 + w * 32 + ni * 16 + fm;
#pragma unroll
        for (int mi = 0; mi < 4; mi++)
#pragma unroll
            for (int r = 0; r < 4; r++) {
                const int row = mi * 16 + quad * 4 + r;
                const long idx = (long)(bb * 256 + m0 + row) * 512 + col;
                const float x = acc2[mi][ni][r]
                    + __bfloat162float(qh[idx]) + __bfloat162float(ql[idx]);
                split_store(x, oh, ol, idx);
            }
    }
}

// ---------------------------------------------------------------------------
// plain-bf16 decoder GEMM, single dispatch, XCD swizzle (verified round 7).
// ---------------------------------------------------------------------------
template<bool SQLOSS>
__global__ __launch_bounds__(256, 3)
void gemm_mfma(const bf* __restrict__ A, const bf* __restrict__ BT,
               bf* __restrict__ C,
               const float* __restrict__ bias,
               const float* __restrict__ Href,
               float* __restrict__ lossAcc,
               int K, int N)
{
    __shared__ __align__(16) char smem[17408];
    bf* Asg = (bf*)smem;
    bf* Bsg = (bf*)(smem + 8192);
    bf* Cs  = (bf*)smem;
    __shared__ float redS[4];

    const int t = threadIdx.x;
    const int flat = blockIdx.y * gridDim.x + blockIdx.x;
    const int lane8 = flat & 7;
    const int grp = flat >> 3;
    const int n_blk = grp % gridDim.x;
    const int m_blk = (grp / gridDim.x) * 8 + lane8;
    const int m0 = m_blk * 128, n0 = n_blk * 128;

    const int w = t >> 6, lane = t & 63;
    const int wm = (w >> 1) * 64, wn = (w & 1) * 64;
    const int fm = lane & 15;
    const int quad = lane >> 4;
    const int fk = quad * 8;
    const int srow = t >> 2, scol = (t & 3) * 8;

    f32x4 acc[4][4];
#pragma unroll
    for (int i = 0; i < 4; i++)
#pragma unroll
        for (int j = 0; j < 4; j++) acc[i][j] = (f32x4){0.f, 0.f, 0.f, 0.f};

    const int nk = K >> 5;
    for (int kt = 0; kt < nk; kt++) {
        const bf* ga = A + (long)(m0 + srow) * K + kt * 32 + scol;
        const bf* gb = BT + (long)(n0 + srow) * K + kt * 32 + scol;
        async_copy16(ga, Asg + w * 512);
        async_copy16(ga + 64L * K, Asg + 2048 + w * 512);
        async_copy16(gb, Bsg + w * 512);
        async_copy16(gb + 64L * K, Bsg + 2048 + w * 512);
        __syncthreads();

        bf16x8 af[4], bfr[4];
#pragma unroll
        for (int mi = 0; mi < 4; mi++)
            af[mi] = *(const bf16x8*)&Asg[(wm + mi * 16 + fm) * 32 + fk];
#pragma unroll
        for (int ni = 0; ni < 4; ni++)
            bfr[ni] = *(const bf16x8*)&Bsg[(wn + ni * 16 + fm) * 32 + fk];
#pragma unroll
        for (int mi = 0; mi < 4; mi++)
#pragma unroll
            for (int ni = 0; ni < 4; ni++)
                acc[mi][ni] = __builtin_amdgcn_mfma_f32_16x16x32_bf16(
                    af[mi], bfr[ni], acc[mi][ni], 0, 0, 0);
        __syncthreads();
    }

    if (SQLOSS) {
        float lsum = 0.f;
#pragma unroll
        for (int ni = 0; ni < 4; ni++) {
            const int col = n0 + wn + ni * 16 + fm;
            const float b = bias[col];
#pragma unroll
            for (int mi = 0; mi < 4; mi++)
#pragma unroll
                for (int r = 0; r < 4; r++) {
                    const int row = m0 + wm + mi * 16 + quad * 4 + r;
                    const float x = fmaxf(acc[mi][ni][r] + b, 0.f);
                    const float d = x - Href[(long)(row / MC) * DIM + col];
                    lsum = fmaf(d, d, lsum);
                }
        }
        lsum = warpReduceSum(lsum);
        if (lane == 0) redS[w] = lsum;
        __syncthreads();
        if (t == 0) atomicAdd(lossAcc, redS[0] + redS[1] + redS[2] + redS[3]);
    } else {
        for (int hf = 0; hf < 2; hf++) {
            if ((w >> 1) == hf) {
#pragma unroll
                for (int ni = 0; ni < 4; ni++) {
                    const int c = wn + ni * 16 + fm;
                    const float bv = bias[n0 + c];
#pragma unroll
                    for (int mi = 0; mi < 4; mi++)
#pragma unroll
                        for (int r = 0; r < 4; r++) {
                            const float x = fmaxf(acc[mi][ni][r] + bv, 0.f);
                            Cs[(mi * 16 + quad * 4 + r) * 136 + c] = __float2bfloat16(x);
                        }
                }
            }
            __syncthreads();
            const int rl2 = t >> 2, cc2 = (t & 3) * 32;
            const long ob = (long)(m0 + hf * 64 + rl2) * N + n0 + cc2;
#pragma unroll
            for (int j = 0; j < 4; j++)
                *(bf16x8*)&C[ob + j * 8] = *(const bf16x8*)&Cs[rl2 * 136 + cc2 + j * 8];
            __syncthreads();
        }
    }
}

// ---------------------------------------------------------------------------
// one conversion kernel: scal zero + H split + ALL weights.
// grid 23040 x 256 = 5,898,240 threads (2,097,152 H + 3,801,088 weights).
// ---------------------------------------------------------------------------
__global__ void conv_all(
    const float* __restrict__ H, bf* __restrict__ h0h, bf* __restrict__ h0l,
    const float* __restrict__ wq, const float* __restrict__ wk,
    const float* __restrict__ wv, const float* __restrict__ wo,
    bf* __restrict__ qkvTh0, bf* __restrict__ qkvTl0,
    bf* __restrict__ woTh0, bf* __restrict__ woTl0,
    bf* __restrict__ qkvTh1, bf* __restrict__ qkvTl1,
    bf* __restrict__ woTh1, bf* __restrict__ woTl1,
    const float* __restrict__ wz, bf* __restrict__ wzTh, bf* __restrict__ wzTl,
    const float* __restrict__ w1, bf* __restrict__ w1T,
    const float* __restrict__ w2, bf* __restrict__ w2T,
    const float* __restrict__ w3, bf* __restrict__ w3T,
    float* __restrict__ scal)
{
    const int t = threadIdx.x;
    if (blockIdx.x == 0 && t < 16) scal[t] = 0.f;
    const int gidx = blockIdx.x * 256 + t;
    if (gidx < 2097152) {           // H -> split planes
        const float x = H[gidx];
        const bf h = __float2bfloat16(x);
        h0h[gidx] = h;
        h0l[gidx] = __float2bfloat16(x - __bfloat162float(h));
        return;
    }
    const int idx = gidx - 2097152;
    if (idx < 2097152) {            // MAB weights, both layers
        const int layer = idx >> 20;
        const int seg = (idx >> 18) & 3;
        const int r = idx & 262143;
        const int k = r >> 9, n = r & 511;
        const float* src = ((seg == 0) ? wq : (seg == 1) ? wk : (seg == 2) ? wv : wo)
                           + (long)layer * 262144;
        const float x = src[r];
        const bf h = __float2bfloat16(x);
        const bf l = __float2bfloat16(x - __bfloat162float(h));
        if (seg < 3) {
            const long o = (long)(seg * 512 + n) * 512 + k;
            if (layer == 0) { qkvTh0[o] = h; qkvTl0[o] = l; }
            else            { qkvTh1[o] = h; qkvTl1[o] = l; }
        } else {
            const long o = (long)n * 512 + k;
            if (layer == 0) { woTh0[o] = h; woTl0[o] = l; }
            else            { woTh1[o] = h; woTl1[o] = l; }
        }
    } else if (idx < 2162688) {     // wz: 512x128 split-T
        const int i = idx - 2097152;
        const int k = i >> 7, n = i & 127;
        const float x = wz[i];
        const bf h = __float2bfloat16(x);
        wzTh[(long)n * 512 + k] = h;
        wzTl[(long)n * 512 + k] = __float2bfloat16(x - __bfloat162float(h));
    } else if (idx < 2228224) {     // w1: 64x1024 plain-T
        const int i = idx - 2162688;
        const int k = i >> 10, n = i & 1023;
        w1T[(long)n * 64 + k] = __float2bfloat16(w1[i]);
    } else if (idx < 3276800) {     // w2: 1024x1024 plain-T
        const int i = idx - 2228224;
        const int k = i >> 10, n = i & 1023;
        w2T[(long)n * 1024 + k] = __float2bfloat16(w2[i]);
    } else if (idx < 3801088) {     // w3: 1024x512 plain-T
        const int i = idx - 3276800;
        const int k = i >> 9, n = i & 511;
        w3T[(long)n * 1024 + k] = __float2bfloat16(w3[i]);
    }
}

// ---------------------------------------------------------------------------
// Cooperative mega-kernel: zgen + em_init + 5x(E-step, M-step) + KL.
// grid 160 blocks (tile = bx%10, b = bx/10) x 256 threads, grid.sync between
// phases. All numerics identical to the round-7 separate kernels.
// ---------------------------------------------------------------------------
__global__ __launch_bounds__(256)
void em_all(const float* __restrict__ stats, const float* __restrict__ eps,
            const int* __restrict__ init_idx,
            float* __restrict__ z, bf* __restrict__ z16,
            float* __restrict__ mu, float* __restrict__ logPi,
            float* __restrict__ musum, float* __restrict__ NkG,
            float* __restrict__ klAcc)
{
    __shared__ float muS[KC][65];
    __shared__ float m2lp[KC];
    __shared__ float postS[KC][256];
    __shared__ float NkS[KC];
    __shared__ float NkU[KC];
    __shared__ float redS[4];

    cg::grid_group grid = cg::this_grid();
    const int bx = blockIdx.x;
    const int tile = bx % 10, b = bx / 10;
    const int t = threadIdx.x;
    const int lane = t & 63, w = t >> 6;

    // ---- phase zgen: 160 blocks x 16 x 256 float4 = 655360 float4 ----
    for (int i = 0; i < 16; i++) {
        const int idx = bx * 4096 + i * 256 + t;
        const int bs = idx / 160;
        const int r = idx % 160;
        const int l4 = r % 16;
        const float4 e = ((const float4*)eps)[idx];
        const float4 mn = ((const float4*)stats)[bs * 32 + l4];
        const float4 lv = ((const float4*)stats)[bs * 32 + 16 + l4];
        float4 zz;
        zz.x = fmaf(e.x, expf(0.5f * lv.x), mn.x);
        zz.y = fmaf(e.y, expf(0.5f * lv.y), mn.y);
        zz.z = fmaf(e.z, expf(0.5f * lv.z), mn.z);
        zz.w = fmaf(e.w, expf(0.5f * lv.w), mn.w);
        ((float4*)z)[idx] = zz;
        bf* zp = z16 + (long)idx * 4;
        zp[0] = __float2bfloat16(zz.x);
        zp[1] = __float2bfloat16(zz.y);
        zp[2] = __float2bfloat16(zz.z);
        zp[3] = __float2bfloat16(zz.w);
    }
    grid.sync();

    // ---- phase init ----
    if (tile == 0) {
        for (int i = t; i < KC * LD; i += 256) {
            const int k = i >> 6, l = i & 63;
            const int idx = init_idx[b * KC + k];
            mu[b * KC * LD + i] = z[((long)b * NPTS + idx) * LD + l];
            musum[b * KC * LD + i] = 0.f;
        }
        if (t < KC) {
            logPi[b * KC + t] = -logf((float)KC);
            NkG[b * KC + t] = 0.f;
        }
    }
    grid.sync();

    // ---- 5 EM iterations ----
    for (int it = 0; it < 5; it++) {
        // E-step + accumulate
        for (int i = t; i < KC * LD; i += 256) muS[i >> 6][i & 63] = mu[b * KC * LD + i];
        __syncthreads();
        if (t < KC) {
            float s = 0.f;
            for (int l = 0; l < LD; l++) { const float m = muS[t][l]; s = fmaf(m, m, s); }
            m2lp[t] = -0.5f * s + logPi[b * KC + t];
        }
        __syncthreads();

        const long n = (long)tile * 256 + t;
        const float* zr = &z[((long)b * NPTS + n) * LD];
        float acc[KC];
#pragma unroll
        for (int k = 0; k < KC; k++) acc[k] = 0.f;
#pragma unroll
        for (int l4 = 0; l4 < 16; l4++) {
            const float4 zv = ((const float4*)zr)[l4];
#pragma unroll
            for (int k = 0; k < KC; k++) {
                acc[k] = fmaf(zv.x, muS[k][l4 * 4 + 0], acc[k]);
                acc[k] = fmaf(zv.y, muS[k][l4 * 4 + 1], acc[k]);
                acc[k] = fmaf(zv.z, muS[k][l4 * 4 + 2], acc[k]);
                acc[k] = fmaf(zv.w, muS[k][l4 * 4 + 3], acc[k]);
            }
        }
        float mx = -1e30f;
        float llv[KC];
#pragma unroll
        for (int k = 0; k < KC; k++) { llv[k] = acc[k] + m2lp[k]; mx = fmaxf(mx, llv[k]); }
        float s = 0.f;
#pragma unroll
        for (int k = 0; k < KC; k++) { llv[k] = expf(llv[k] - mx); s += llv[k]; }
        const float inv = 1.f / s;
#pragma unroll
        for (int k = 0; k < KC; k++) postS[k][t] = llv[k] * inv;
        __syncthreads();

#pragma unroll
        for (int kk = 0; kk < 5; kk++) {
            const int k = w * 5 + kk;
            float p = postS[k][lane] + postS[k][lane + 64] + postS[k][lane + 128] + postS[k][lane + 192];
            p = warpReduceSum(p);
            if (lane == 0) NkS[k] = p;
        }
        __syncthreads();

        const float* zb = &z[((long)b * NPTS + (long)tile * 256) * LD];
#pragma unroll
        for (int j = 0; j < 5; j++) {
            const int o = t + j * 256;
            const int k = o >> 6, l = o & 63;
            float sacc = 0.f;
            for (int n2 = 0; n2 < 256; n2++)
                sacc = fmaf(postS[k][n2], zb[n2 * LD + l], sacc);
            atomicAdd(&musum[b * KC * LD + o], sacc);
        }
        if (t < KC) atomicAdd(&NkG[b * KC + t], NkS[t]);
        grid.sync();

        // M-step (16 blocks)
        if (tile == 0) {
            if (t < KC) NkU[t] = NkG[b * KC + t];
            __syncthreads();
            float sn = 0.f;
            for (int k = 0; k < KC; k++) sn += NkU[k];
            if (t < KC) logPi[b * KC + t] = logf(NkU[t] / sn);
            for (int i = t; i < KC * LD; i += 256) {
                mu[b * KC * LD + i] = musum[b * KC * LD + i] / NkU[i >> 6];
                musum[b * KC * LD + i] = 0.f;
            }
            __syncthreads();
            if (t < KC) NkG[b * KC + t] = 0.f;
        }
        grid.sync();
    }

    // ---- phase KL ----
    for (int i = t; i < KC * LD; i += 256) muS[i >> 6][i & 63] = mu[b * KC * LD + i];
    __syncthreads();
    if (t < KC) {
        float s = 0.f;
        for (int l = 0; l < LD; l++) { const float m = muS[t][l]; s = fmaf(m, m, s); }
        m2lp[t] = -0.5f * s + logPi[b * KC + t];
    }
    __syncthreads();

    {
        const int n = tile * 256 + t;
        const int sidx = n / MC, m = n % MC;
        const long bs = (long)b * SEQ + sidx;
        const float* zr = &z[((long)b * NPTS + n) * LD];

        float acc[KC];
#pragma unroll
        for (int k = 0; k < KC; k++) acc[k] = 0.f;
        float x2 = 0.f;
#pragma unroll
        for (int l4 = 0; l4 < 16; l4++) {
            const float4 zv = ((const float4*)zr)[l4];
            x2 = fmaf(zv.x, zv.x, fmaf(zv.y, zv.y, fmaf(zv.z, zv.z, fmaf(zv.w, zv.w, x2))));
#pragma unroll
            for (int k = 0; k < KC; k++) {
                acc[k] = fmaf(zv.x, muS[k][l4 * 4 + 0], acc[k]);
                acc[k] = fmaf(zv.y, muS[k][l4 * 4 + 1], acc[k]);
                acc[k] = fmaf(zv.z, muS[k][l4 * 4 + 2], acc[k]);
                acc[k] = fmaf(zv.w, muS[k][l4 * 4 + 3], acc[k]);
            }
        }
        float mx = -1e30f;
        float llv[KC];
#pragma unroll
        for (int k = 0; k < KC; k++) { llv[k] = acc[k] + m2lp[k]; mx = fmaxf(mx, llv[k]); }
        float s = 0.f;
#pragma unroll
        for (int k = 0; k < KC; k++) s += expf(llv[k] - mx);
        const float log_pz = -0.5f * x2 + mx + logf(s) + LD * LOG_NORM;

        const float* lvr = &stats[bs * 128 + 64];
        const float* er = &eps[(bs * MC + m) * LD];
        float slv = 0.f, se2 = 0.f;
#pragma unroll
        for (int l4 = 0; l4 < 16; l4++) {
            const float4 lv = ((const float4*)lvr)[l4];
            slv += lv.x + lv.y + lv.z + lv.w;
            const float4 e = ((const float4*)er)[l4];
            se2 = fmaf(e.x, e.x, fmaf(e.y, e.y, fmaf(e.z, e.z, fmaf(e.w, e.w, se2))));
        }
        const float log_qz = -0.5f * (slv + se2) + LD * LOG_NORM;

        float v = log_qz - log_pz;
        v = warpReduceSum(v);
        if ((t & 63) == 0) redS[t >> 6] = v;
        __syncthreads();
        if (t == 0) atomicAdd(klAcc, redS[0] + redS[1] + redS[2] + redS[3]);
    }
}

__global__ void finalize(const float* __restrict__ scal, float* __restrict__ out)
{
    if (threadIdx.x == 0) {
        out[0] = scal[0] * (1.f / (float)NROWS);
        out[1] = scal[1] * (1.f / (float)NROWS);
    }
}

// ---------------------------------------------------------------------------
extern "C" void kernel_launch(void* const* d_in, const int* in_sizes, int n_in,
                              void* d_out, int out_size, void* d_ws, size_t ws_size,
                              hipStream_t stream)
{
    const float* H   = (const float*)d_in[0];
    const float* eps = (const float*)d_in[1];
    const float* wq  = (const float*)d_in[2];
    const float* bq  = (const float*)d_in[3];
    const float* wk  = (const float*)d_in[4];
    const float* bk  = (const float*)d_in[5];
    const float* wv  = (const float*)d_in[6];
    const float* bv  = (const float*)d_in[7];
    const float* wo  = (const float*)d_in[8];
    const float* bo  = (const float*)d_in[9];
    const float* wz  = (const float*)d_in[10];
    const float* bz  = (const float*)d_in[11];
    const float* w1  = (const float*)d_in[12];
    const float* b1  = (const float*)d_in[13];
    const float* w2  = (const float*)d_in[14];
    const float* b2  = (const float*)d_in[15];
    const float* w3  = (const float*)d_in[16];
    const float* b3  = (const float*)d_in[17];
    const int* init_idx = (const int*)d_in[18];
    float* out = (float*)d_out;
    float* wsf = (float*)d_ws;

    // ---- workspace layout (float slots), ws = 256 MiB, used ~240 MB ----
    const long o_scal  = 0;
    const long o_NkG   = 1024;
    const long o_musum = 2048;
    const long o_logpi = 23552;
    const long o_mu    = 24576;
    const long o_q     = 45056;
    const long o_k     = 2142208;
    const long o_vT    = 4239360;
    const long o_o     = 6336512;
    const long o_h1    = 8433664;
    const long o_qkvT0 = 10530816;
    const long o_woT0  = 11317248;
    const long o_qkvT1 = 11579392;
    const long o_woT1  = 12365824;
    const long o_wzT   = 12627968;
    const long o_st    = 12693504;
    const long o_zb    = 13217792;
    const long o_z16   = 15839232;
    const long o_w1T   = 17149952;
    const long o_w2T   = 17182720;
    const long o_w3T   = 17707008;
    const long o_d1    = 17969152;
    const long o_d2    = 38940672;   // ends 59912192 (239.6 MB)

    const long PL = (long)BS_TOT * DIM;
    bf* qh  = (bf*)(wsf + o_q);   bf* ql  = qh + PL;
    bf* kh  = (bf*)(wsf + o_k);   bf* kl_ = kh + PL;
    bf* vTh = (bf*)(wsf + o_vT);  bf* vTl = vTh + PL;
    bf* oh  = (bf*)(wsf + o_o);   bf* ol  = oh + PL;
    bf* h1h = (bf*)(wsf + o_h1);  bf* h1l = h1h + PL;
    bf* h2h = qh;                 bf* h2l = ql;
    bf* qkvTh0 = (bf*)(wsf + o_qkvT0); bf* qkvTl0 = qkvTh0 + 1536L * 512;
    bf* woTh0  = (bf*)(wsf + o_woT0);  bf* woTl0  = woTh0 + 512L * 512;
    bf* qkvTh1 = (bf*)(wsf + o_qkvT1); bf* qkvTl1 = qkvTh1 + 1536L * 512;
    bf* woTh1  = (bf*)(wsf + o_woT1);  bf* woTl1  = woTh1 + 512L * 512;
    bf* wzTh = (bf*)(wsf + o_wzT);     bf* wzTl = wzTh + 128L * 512;
    bf* w1T = (bf*)(wsf + o_w1T);
    bf* w2T = (bf*)(wsf + o_w2T);
    bf* w3T = (bf*)(wsf + o_w3T);
    bf* z16 = (bf*)(wsf + o_z16);
    bf* d1  = (bf*)(wsf + o_d1);
    bf* d2  = (bf*)(wsf + o_d2);
    float* st = wsf + o_st;
    float* zb = wsf + o_zb;
    float* scal = wsf + o_scal;
    float* muP = wsf + o_mu;
    float* lpP = wsf + o_logpi;
    float* msP = wsf + o_musum;
    float* nkP = wsf + o_NkG;

    const dim3 blk(256);

    // ---- all conversions + scal zero, one launch ----
    conv_all<<<23040, blk, 0, stream>>>(
        H, h1h, h1l,
        wq, wk, wv, wo,
        qkvTh0, qkvTl0, woTh0, woTl0,
        qkvTh1, qkvTl1, woTh1, woTl1,
        wz, wzTh, wzTl, w1, w1T, w2, w2T, w3, w3T, scal);

    // ---- 2x MAB on split-bf16 MFMA ----
    for (int i = 0; i < 2; i++) {
        const long boff = (long)i * DIM;
        bf* qkh = i ? qkvTh1 : qkvTh0;  bf* qkl = i ? qkvTl1 : qkvTl0;
        bf* wh  = i ? woTh1 : woTh0;    bf* wl  = i ? woTl1 : woTl0;

        gemm3t<0><<<dim3(12, 64), blk, 0, stream>>>(
            h1h, h1l, qkh, qkl, 512, 512, 512,
            bq + boff, bk + boff, bv + boff, nullptr,
            qh, ql, kh, kl_, vTh, vTl, nullptr, nullptr);
        attn_fused<<<dim3(4, 64), blk, 0, stream>>>(qh, ql, kh, kl_, vTh, vTl, oh, ol);
        bf* houth = (i == 0) ? h1h : h2h;
        bf* houtl = (i == 0) ? h1l : h2l;
        gemm3t<3><<<dim3(4, 64), blk, 0, stream>>>(
            oh, ol, wh, wl, 512, 512, 512,
            bo + boff, nullptr, nullptr, nullptr,
            houth, houtl, nullptr, nullptr, nullptr, nullptr, oh, ol);
    }

    // ---- stats = h2 @ wz + bz ----
    gemm3t<4><<<dim3(1, 64), blk, 0, stream>>>(
        h2h, h2l, wzTh, wzTl, 512, 512, 512,
        bz, nullptr, nullptr, st,
        nullptr, nullptr, nullptr, nullptr, nullptr, nullptr, nullptr, nullptr);

    // ---- cooperative zgen + EM + KL, one dispatch ----
    {
        const float* st_c = st;
        const float* eps_c = eps;
        const int* ii_c = init_idx;
        float* z_p = zb;  bf* z16_p = z16;
        float* kl_p = scal + 1;
        void* kargs[] = { (void*)&st_c, (void*)&eps_c, (void*)&ii_c,
                          (void*)&z_p, (void*)&z16_p,
                          (void*)&muP, (void*)&lpP, (void*)&msP, (void*)&nkP,
                          (void*)&kl_p };
        hipLaunchCooperativeKernel((void*)em_all, dim3(160), blk, kargs, 0, stream);
    }

    // ---- decoder MLP + fused rec_loss (z16 written by em_all's zgen) ----
    gemm_mfma<false><<<dim3(8, 320), blk, 0, stream>>>(
        z16, w1T, d1, b1, nullptr, nullptr, 64, 1024);
    gemm_mfma<false><<<dim3(8, 320), blk, 0, stream>>>(
        d1, w2T, d2, b2, nullptr, nullptr, 1024, 1024);
    gemm_mfma<true><<<dim3(4, 320), blk, 0, stream>>>(
        d2, w3T, nullptr, b3, H, scal + 0, 1024, 512);

    finalize<<<1, 64, 0, stream>>>(scal, out);
}

// Round 9
// 694.188 us; speedup vs baseline: 2.0934x; 2.0934x over previous
//
#include <hip/hip_runtime.h>
#include <hip/hip_bf16.h>
#include <math.h>

// ---------------------------------------------------------------------------
// GMVAE fused pipeline. Round 9: revert cooperative EM (grid.sync = ~75us/sync
// on MI355X — measured round 8). Instead: ping-pong EM accumulators, M-step
// folded into each E-step block (redundant per-block divide), em_update gone.
// EM+KL: 12 dispatches -> 7, no grid sync.  Rest identical to round 7 (714us).
// ---------------------------------------------------------------------------

#define BATCH 16
#define SEQ 256
#define DIM 512
#define NH 4
#define DH 128
#define LD 64
#define KC 20
#define MC 10
#define NPTS 2560
#define BS_TOT 4096
#define NROWS 40960
#define LOG_NORM (-0.9189385332046727f)

typedef __attribute__((ext_vector_type(8))) short bf16x8;
typedef __attribute__((ext_vector_type(4))) float f32x4;
typedef __hip_bfloat16 bf;

__device__ inline float warpReduceSum(float v) {
    for (int o = 32; o > 0; o >>= 1) v += __shfl_down(v, o);
    return v;
}

__device__ inline void async_copy16(const bf* g, bf* l) {
    __builtin_amdgcn_global_load_lds(
        (const __attribute__((address_space(1))) unsigned int*)g,
        (__attribute__((address_space(3))) unsigned int*)l, 16, 0, 0);
}

__device__ inline void split_store(float x, bf* ph, bf* pl, long idx) {
    const bf h = __float2bfloat16(x);
    ph[idx] = h;
    pl[idx] = __float2bfloat16(x - __bfloat162float(h));
}

// ---------------------------------------------------------------------------
// Split-bf16 MFMA GEMM, 64x128 tile, BK=32 (verified round 6/7).
// MODE: 0=QKV(fused q/k/vT out) 3=OPROJ(bias,relu,+resid) 4=STATS(fp32+bias)
// ---------------------------------------------------------------------------
template<int MODE>
__global__ __launch_bounds__(256, 3)
void gemm3t(const bf* __restrict__ Ah, const bf* __restrict__ Al,
            const bf* __restrict__ Bh, const bf* __restrict__ Bl,
            int K, int lda, int ldb,
            const float* __restrict__ b0, const float* __restrict__ b1v,
            const float* __restrict__ b2v,
            float* __restrict__ outF,
            bf* __restrict__ P1h, bf* __restrict__ P1l,
            bf* __restrict__ P2h, bf* __restrict__ P2l,
            bf* __restrict__ P3h, bf* __restrict__ P3l,
            const bf* __restrict__ Rh, const bf* __restrict__ Rl)
{
    __shared__ __align__(16) char smem[24576];
    bf* Ash = (bf*)smem;
    bf* Asl = (bf*)(smem + 4096);
    bf* Bsh = (bf*)(smem + 8192);
    bf* Bsl = (bf*)(smem + 16384);
    float* Xs = (float*)smem;        // epilogue overlay [64][68]

    const int t = threadIdx.x;
    const int m0 = blockIdx.y * 64, n0 = blockIdx.x * 128;
    const int w = t >> 6, lane = t & 63;
    const int wn = w * 32;
    const int fm = lane & 15, quad = lane >> 4, fk = quad * 8;
    const int srow = t >> 2, scol = (t & 3) * 8;

    f32x4 acc[4][2];
#pragma unroll
    for (int i = 0; i < 4; i++)
#pragma unroll
        for (int j = 0; j < 2; j++) acc[i][j] = (f32x4){0.f, 0.f, 0.f, 0.f};

    const int nk = K >> 5;
    for (int kk = 0; kk < nk; kk++) {
        const long ao = (long)(m0 + srow) * lda + kk * 32 + scol;
        const long bo = (long)(n0 + srow) * ldb + kk * 32 + scol;
        async_copy16(Ah + ao, Ash + w * 512);
        async_copy16(Al + ao, Asl + w * 512);
        async_copy16(Bh + bo, Bsh + w * 512);
        async_copy16(Bh + bo + 64L * ldb, Bsh + 2048 + w * 512);
        async_copy16(Bl + bo, Bsl + w * 512);
        async_copy16(Bl + bo + 64L * ldb, Bsl + 2048 + w * 512);
        __syncthreads();

        bf16x8 afh[4], afl[4], bfh[2], bfl[2];
#pragma unroll
        for (int mi = 0; mi < 4; mi++) {
            afh[mi] = *(const bf16x8*)&Ash[(mi * 16 + fm) * 32 + fk];
            afl[mi] = *(const bf16x8*)&Asl[(mi * 16 + fm) * 32 + fk];
        }
#pragma unroll
        for (int ni = 0; ni < 2; ni++) {
            bfh[ni] = *(const bf16x8*)&Bsh[(wn + ni * 16 + fm) * 32 + fk];
            bfl[ni] = *(const bf16x8*)&Bsl[(wn + ni * 16 + fm) * 32 + fk];
        }
#pragma unroll
        for (int mi = 0; mi < 4; mi++)
#pragma unroll
            for (int ni = 0; ni < 2; ni++) {
                acc[mi][ni] = __builtin_amdgcn_mfma_f32_16x16x32_bf16(
                    afh[mi], bfh[ni], acc[mi][ni], 0, 0, 0);
                acc[mi][ni] = __builtin_amdgcn_mfma_f32_16x16x32_bf16(
                    afh[mi], bfl[ni], acc[mi][ni], 0, 0, 0);
                acc[mi][ni] = __builtin_amdgcn_mfma_f32_16x16x32_bf16(
                    afl[mi], bfh[ni], acc[mi][ni], 0, 0, 0);
            }
        __syncthreads();
    }

    const int rl = t >> 2;
    const int cc4 = (t & 3) * 16;

    for (int p = 0; p < 2; p++) {
        if ((w >> 1) == p) {
            const int cb = wn - p * 64;
#pragma unroll
            for (int mi = 0; mi < 4; mi++)
#pragma unroll
                for (int ni = 0; ni < 2; ni++) {
                    const int c = cb + ni * 16 + fm;
#pragma unroll
                    for (int r = 0; r < 4; r++)
                        Xs[(mi * 16 + quad * 4 + r) * 68 + c] = acc[mi][ni][r];
                }
        }
        __syncthreads();

        if (MODE == 0 && n0 >= 1024) {
            const int hh = (n0 >> 7) & 3;
            const int dd = p * 64 + rl;
            const int bb = m0 >> 8;
            const int sb = (m0 & 255) + cc4;
            const float bias = b2v[hh * 128 + dd];
            const long ob = (((long)(bb * NH + hh) * DH + dd) << 8) + sb;
#pragma unroll
            for (int j = 0; j < 2; j++) {
                bf16x8 vh, vl;
#pragma unroll
                for (int i = 0; i < 8; i++) {
                    const float x = Xs[(cc4 + j * 8 + i) * 68 + rl] + bias;
                    const bf h = __float2bfloat16(x);
                    vh[i] = *(const short*)&h;
                    const bf l = __float2bfloat16(x - __bfloat162float(h));
                    vl[i] = *(const short*)&l;
                }
                *(bf16x8*)&P3h[ob + j * 8] = vh;
                *(bf16x8*)&P3l[ob + j * 8] = vl;
            }
        } else {
            float xv[16];
#pragma unroll
            for (int i = 0; i < 4; i++)
                *(float4*)&xv[i * 4] = *(const float4*)&Xs[rl * 68 + cc4 + i * 4];

            if (MODE == 0) {
                const int which = n0 >> 9;
                const int colq = (n0 & 511) + p * 64 + cc4;
                const float* bias = which ? b1v : b0;
                bf* Ph = which ? P2h : P1h;
                bf* Pl = which ? P2l : P1l;
                const long ob = (long)(m0 + rl) * 512 + colq;
#pragma unroll
                for (int j = 0; j < 2; j++) {
                    bf16x8 vh, vl;
#pragma unroll
                    for (int i = 0; i < 8; i++) {
                        const float x = xv[j * 8 + i] + bias[colq + j * 8 + i];
                        const bf h = __float2bfloat16(x); vh[i] = *(const short*)&h;
                        const bf l = __float2bfloat16(x - __bfloat162float(h));
                        vl[i] = *(const short*)&l;
                    }
                    *(bf16x8*)&Ph[ob + j * 8] = vh;
                    *(bf16x8*)&Pl[ob + j * 8] = vl;
                }
            } else if (MODE == 3) {
                const int colg = n0 + p * 64 + cc4;
                const long ob = (long)(m0 + rl) * 512 + colg;
#pragma unroll
                for (int j = 0; j < 2; j++) {
                    const bf16x8 rh = *(const bf16x8*)&Rh[ob + j * 8];
                    const bf16x8 rv = *(const bf16x8*)&Rl[ob + j * 8];
                    bf16x8 vh, vl;
#pragma unroll
                    for (int i = 0; i < 8; i++) {
                        short sh = rh[i], sl = rv[i];
                        float x = fmaxf(xv[j * 8 + i] + b0[colg + j * 8 + i], 0.f)
                                + __bfloat162float(*(const bf*)&sh)
                                + __bfloat162float(*(const bf*)&sl);
                        const bf h = __float2bfloat16(x); vh[i] = *(const short*)&h;
                        const bf l = __float2bfloat16(x - __bfloat162float(h));
                        vl[i] = *(const short*)&l;
                    }
                    *(bf16x8*)&P1h[ob + j * 8] = vh;
                    *(bf16x8*)&P1l[ob + j * 8] = vl;
                }
            } else {
                const int colg = p * 64 + cc4;
                const long ob = (long)(m0 + rl) * 128 + colg;
#pragma unroll
                for (int i = 0; i < 4; i++) {
                    float4 v = *(float4*)&xv[i * 4];
                    v.x += b0[colg + i * 4 + 0];
                    v.y += b0[colg + i * 4 + 1];
                    v.z += b0[colg + i * 4 + 2];
                    v.w += b0[colg + i * 4 + 3];
                    *(float4*)&outF[ob + i * 4] = v;
                }
            }
        }
        __syncthreads();
    }
}

// ---------------------------------------------------------------------------
// Fused attention (unchanged, verified).
// ---------------------------------------------------------------------------
__global__ __launch_bounds__(256)
void attn_fused(const bf* __restrict__ qh, const bf* __restrict__ ql,
                const bf* __restrict__ kh, const bf* __restrict__ kl,
                const bf* __restrict__ vTh, const bf* __restrict__ vTl,
                bf* __restrict__ oh, bf* __restrict__ ol)
{
    __shared__ __align__(16) char smem[43008];
    bf* Qsh = (bf*)smem;            bf* Qsl = (bf*)(smem + 4096);
    bf* Ksh = (bf*)(smem + 8192);   bf* Ksl = (bf*)(smem + 24576);
    bf* Psh = (bf*)smem;            bf* Psl = (bf*)(smem + 4096);
    bf* Vsh = (bf*)(smem + 8192);   bf* Vsl = (bf*)(smem + 16384);
    float (*red)[4]  = (float(*)[4])(smem + 40960);
    float (*red2)[4] = (float(*)[4])(smem + 41984);

    const int t = threadIdx.x;
    const int z = blockIdx.y;
    const int m0 = blockIdx.x * 64;
    const int bb = z >> 2, hh = z & 3;
    const long hOff = (long)bb * 131072 + (long)hh * 128;
    const long vOff = (long)z * 32768;

    const int w = t >> 6, lane = t & 63;
    const int fm = lane & 15;
    const int quad = lane >> 4;
    const int fk = quad * 8;
    const int srow = t >> 2, scol = (t & 3) * 8;

    f32x4 acc[4][4];
#pragma unroll
    for (int i = 0; i < 4; i++)
#pragma unroll
        for (int j = 0; j < 4; j++) acc[i][j] = (f32x4){0.f, 0.f, 0.f, 0.f};

    for (int kk = 0; kk < 4; kk++) {
        const long ao = hOff + (long)(m0 + srow) * 512 + kk * 32 + scol;
        const long bo = hOff + (long)srow * 512 + kk * 32 + scol;
        async_copy16(qh + ao, Qsh + w * 512);
        async_copy16(ql + ao, Qsl + w * 512);
#pragma unroll
        for (int j = 0; j < 4; j++) {
            async_copy16(kh + bo + (long)j * 64 * 512, Ksh + w * 512 + j * 2048);
            async_copy16(kl + bo + (long)j * 64 * 512, Ksl + w * 512 + j * 2048);
        }
        __syncthreads();

        bf16x8 afh[4], afl[4];
#pragma unroll
        for (int mi = 0; mi < 4; mi++) {
            afh[mi] = *(const bf16x8*)&Qsh[(mi * 16 + fm) * 32 + fk];
            afl[mi] = *(const bf16x8*)&Qsl[(mi * 16 + fm) * 32 + fk];
        }
#pragma unroll
        for (int ni = 0; ni < 4; ni++) {
            const bf16x8 bh = *(const bf16x8*)&Ksh[(w * 64 + ni * 16 + fm) * 32 + fk];
            const bf16x8 bl = *(const bf16x8*)&Ksl[(w * 64 + ni * 16 + fm) * 32 + fk];
#pragma unroll
            for (int mi = 0; mi < 4; mi++) {
                acc[mi][ni] = __builtin_amdgcn_mfma_f32_16x16x32_bf16(
                    afh[mi], bh, acc[mi][ni], 0, 0, 0);
                acc[mi][ni] = __builtin_amdgcn_mfma_f32_16x16x32_bf16(
                    afh[mi], bl, acc[mi][ni], 0, 0, 0);
                acc[mi][ni] = __builtin_amdgcn_mfma_f32_16x16x32_bf16(
                    afl[mi], bh, acc[mi][ni], 0, 0, 0);
            }
        }
        __syncthreads();
    }

    const float alpha = 0.044194173824159216f;
#pragma unroll
    for (int mi = 0; mi < 4; mi++)
#pragma unroll
        for (int r = 0; r < 4; r++) {
            float m = -1e30f;
#pragma unroll
            for (int ni = 0; ni < 4; ni++) m = fmaxf(m, acc[mi][ni][r]);
            for (int o = 8; o > 0; o >>= 1) m = fmaxf(m, __shfl_xor(m, o));
            if (fm == 0) red[mi * 16 + quad * 4 + r][w] = m;
        }
    __syncthreads();
    float invr[4][4];
#pragma unroll
    for (int mi = 0; mi < 4; mi++)
#pragma unroll
        for (int r = 0; r < 4; r++) {
            const int rowl = mi * 16 + quad * 4 + r;
            const float mx = fmaxf(fmaxf(red[rowl][0], red[rowl][1]),
                                   fmaxf(red[rowl][2], red[rowl][3]));
            float s = 0.f;
#pragma unroll
            for (int ni = 0; ni < 4; ni++) {
                const float e = __expf((acc[mi][ni][r] - mx) * alpha);
                acc[mi][ni][r] = e;
                s += e;
            }
            for (int o = 8; o > 0; o >>= 1) s += __shfl_xor(s, o);
            if (fm == 0) red2[rowl][w] = s;
        }
    __syncthreads();
#pragma unroll
    for (int mi = 0; mi < 4; mi++)
#pragma unroll
        for (int r = 0; r < 4; r++) {
            const int rowl = mi * 16 + quad * 4 + r;
            invr[mi][r] = 1.f / (red2[rowl][0] + red2[rowl][1] + red2[rowl][2] + red2[rowl][3]);
        }

    f32x4 acc2[4][2];
#pragma unroll
    for (int i = 0; i < 4; i++)
#pragma unroll
        for (int j = 0; j < 2; j++) acc2[i][j] = (f32x4){0.f, 0.f, 0.f, 0.f};

    for (int kc = 0; kc < 8; kc++) {
        if (w == (kc >> 1)) {
            const int nib = (kc & 1) * 2;
#pragma unroll
            for (int mi = 0; mi < 4; mi++)
#pragma unroll
                for (int r = 0; r < 4; r++) {
                    const int row = mi * 16 + quad * 4 + r;
#pragma unroll
                    for (int j = 0; j < 2; j++) {
                        const float p = acc[mi][nib + j][r] * invr[mi][r];
                        const int cc = j * 16 + fm;
                        const bf h = __float2bfloat16(p);
                        Psh[row * 32 + cc] = h;
                        Psl[row * 32 + cc] = __float2bfloat16(p - __bfloat162float(h));
                    }
                }
        }
        const long vo = vOff + (long)srow * 256 + kc * 32 + scol;
        async_copy16(vTh + vo, Vsh + w * 512);
        async_copy16(vTh + vo + 64L * 256, Vsh + w * 512 + 2048);
        async_copy16(vTl + vo, Vsl + w * 512);
        async_copy16(vTl + vo + 64L * 256, Vsl + w * 512 + 2048);
        __syncthreads();

        bf16x8 pfh[4], pfl[4];
#pragma unroll
        for (int mi = 0; mi < 4; mi++) {
            pfh[mi] = *(const bf16x8*)&Psh[(mi * 16 + fm) * 32 + fk];
            pfl[mi] = *(const bf16x8*)&Psl[(mi * 16 + fm) * 32 + fk];
        }
#pragma unroll
        for (int ni = 0; ni < 2; ni++) {
            const bf16x8 vh = *(const bf16x8*)&Vsh[(w * 32 + ni * 16 + fm) * 32 + fk];
            const bf16x8 vl = *(const bf16x8*)&Vsl[(w * 32 + ni * 16 + fm) * 32 + fk];
#pragma unroll
            for (int mi = 0; mi < 4; mi++) {
                acc2[mi][ni] = __builtin_amdgcn_mfma_f32_16x16x32_bf16(
                    pfh[mi], vh, acc2[mi][ni], 0, 0, 0);
                acc2[mi][ni] = __builtin_amdgcn_mfma_f32_16x16x32_bf16(
                    pfh[mi], vl, acc2[mi][ni], 0, 0, 0);
                acc2[mi][ni] = __builtin_amdgcn_mfma_f32_16x16x32_bf16(
                    pfl[mi], vh, acc2[mi][ni], 0, 0, 0);
            }
        }
        __syncthreads();
    }

#pragma unroll
    for (int ni = 0; ni < 2; ni++) {
        const int col = hh * 128 + w * 32 + ni * 16 + fm;
#pragma unroll
        for (int mi = 0; mi < 4; mi++)
#pragma unroll
            for (int r = 0; r < 4; r++) {
                const int row = mi * 16 + quad * 4 + r;
                const long idx = (long)(bb * 256 + m0 + row) * 512 + col;
                const float x = acc2[mi][ni][r]
                    + __bfloat162float(qh[idx]) + __bfloat162float(ql[idx]);
                split_store(x, oh, ol, idx);
            }
    }
}

// ---------------------------------------------------------------------------
// plain-bf16 decoder GEMM, single dispatch, XCD swizzle (verified round 7).
// ---------------------------------------------------------------------------
template<bool SQLOSS>
__global__ __launch_bounds__(256, 3)
void gemm_mfma(const bf* __restrict__ A, const bf* __restrict__ BT,
               bf* __restrict__ C,
               const float* __restrict__ bias,
               const float* __restrict__ Href,
               float* __restrict__ lossAcc,
               int K, int N)
{
    __shared__ __align__(16) char smem[17408];
    bf* Asg = (bf*)smem;
    bf* Bsg = (bf*)(smem + 8192);
    bf* Cs  = (bf*)smem;
    __shared__ float redS[4];

    const int t = threadIdx.x;
    const int flat = blockIdx.y * gridDim.x + blockIdx.x;
    const int lane8 = flat & 7;
    const int grp = flat >> 3;
    const int n_blk = grp % gridDim.x;
    const int m_blk = (grp / gridDim.x) * 8 + lane8;
    const int m0 = m_blk * 128, n0 = n_blk * 128;

    const int w = t >> 6, lane = t & 63;
    const int wm = (w >> 1) * 64, wn = (w & 1) * 64;
    const int fm = lane & 15;
    const int quad = lane >> 4;
    const int fk = quad * 8;
    const int srow = t >> 2, scol = (t & 3) * 8;

    f32x4 acc[4][4];
#pragma unroll
    for (int i = 0; i < 4; i++)
#pragma unroll
        for (int j = 0; j < 4; j++) acc[i][j] = (f32x4){0.f, 0.f, 0.f, 0.f};

    const int nk = K >> 5;
    for (int kt = 0; kt < nk; kt++) {
        const bf* ga = A + (long)(m0 + srow) * K + kt * 32 + scol;
        const bf* gb = BT + (long)(n0 + srow) * K + kt * 32 + scol;
        async_copy16(ga, Asg + w * 512);
        async_copy16(ga + 64L * K, Asg + 2048 + w * 512);
        async_copy16(gb, Bsg + w * 512);
        async_copy16(gb + 64L * K, Bsg + 2048 + w * 512);
        __syncthreads();

        bf16x8 af[4], bfr[4];
#pragma unroll
        for (int mi = 0; mi < 4; mi++)
            af[mi] = *(const bf16x8*)&Asg[(wm + mi * 16 + fm) * 32 + fk];
#pragma unroll
        for (int ni = 0; ni < 4; ni++)
            bfr[ni] = *(const bf16x8*)&Bsg[(wn + ni * 16 + fm) * 32 + fk];
#pragma unroll
        for (int mi = 0; mi < 4; mi++)
#pragma unroll
            for (int ni = 0; ni < 4; ni++)
                acc[mi][ni] = __builtin_amdgcn_mfma_f32_16x16x32_bf16(
                    af[mi], bfr[ni], acc[mi][ni], 0, 0, 0);
        __syncthreads();
    }

    if (SQLOSS) {
        float lsum = 0.f;
#pragma unroll
        for (int ni = 0; ni < 4; ni++) {
            const int col = n0 + wn + ni * 16 + fm;
            const float b = bias[col];
#pragma unroll
            for (int mi = 0; mi < 4; mi++)
#pragma unroll
                for (int r = 0; r < 4; r++) {
                    const int row = m0 + wm + mi * 16 + quad * 4 + r;
                    const float x = fmaxf(acc[mi][ni][r] + b, 0.f);
                    const float d = x - Href[(long)(row / MC) * DIM + col];
                    lsum = fmaf(d, d, lsum);
                }
        }
        lsum = warpReduceSum(lsum);
        if (lane == 0) redS[w] = lsum;
        __syncthreads();
        if (t == 0) atomicAdd(lossAcc, redS[0] + redS[1] + redS[2] + redS[3]);
    } else {
        for (int hf = 0; hf < 2; hf++) {
            if ((w >> 1) == hf) {
#pragma unroll
                for (int ni = 0; ni < 4; ni++) {
                    const int c = wn + ni * 16 + fm;
                    const float bv = bias[n0 + c];
#pragma unroll
                    for (int mi = 0; mi < 4; mi++)
#pragma unroll
                        for (int r = 0; r < 4; r++) {
                            const float x = fmaxf(acc[mi][ni][r] + bv, 0.f);
                            Cs[(mi * 16 + quad * 4 + r) * 136 + c] = __float2bfloat16(x);
                        }
                }
            }
            __syncthreads();
            const int rl2 = t >> 2, cc2 = (t & 3) * 32;
            const long ob = (long)(m0 + hf * 64 + rl2) * N + n0 + cc2;
#pragma unroll
            for (int j = 0; j < 4; j++)
                *(bf16x8*)&C[ob + j * 8] = *(const bf16x8*)&Cs[rl2 * 136 + cc2 + j * 8];
            __syncthreads();
        }
    }
}

// ---------------------------------------------------------------------------
// one conversion kernel: scal zero + H split + ALL weights + EM buffer zero.
// total indices: 2097152 (H) + 3801088 (weights) + 104000 (EM zero) = 6002240
// grid 23447 x 256.
// ---------------------------------------------------------------------------
__global__ void conv_all(
    const float* __restrict__ H, bf* __restrict__ h0h, bf* __restrict__ h0l,
    const float* __restrict__ wq, const float* __restrict__ wk,
    const float* __restrict__ wv, const float* __restrict__ wo,
    bf* __restrict__ qkvTh0, bf* __restrict__ qkvTl0,
    bf* __restrict__ woTh0, bf* __restrict__ woTl0,
    bf* __restrict__ qkvTh1, bf* __restrict__ qkvTl1,
    bf* __restrict__ woTh1, bf* __restrict__ woTl1,
    const float* __restrict__ wz, bf* __restrict__ wzTh, bf* __restrict__ wzTl,
    const float* __restrict__ w1, bf* __restrict__ w1T,
    const float* __restrict__ w2, bf* __restrict__ w2T,
    const float* __restrict__ w3, bf* __restrict__ w3T,
    float* __restrict__ scal, float* __restrict__ msP, float* __restrict__ nkP)
{
    const int t = threadIdx.x;
    if (blockIdx.x == 0 && t < 16) scal[t] = 0.f;
    const int gidx = blockIdx.x * 256 + t;
    if (gidx < 2097152) {           // H -> split planes
        const float x = H[gidx];
        const bf h = __float2bfloat16(x);
        h0h[gidx] = h;
        h0l[gidx] = __float2bfloat16(x - __bfloat162float(h));
        return;
    }
    const int idx = gidx - 2097152;
    if (idx < 2097152) {            // MAB weights, both layers
        const int layer = idx >> 20;
        const int seg = (idx >> 18) & 3;
        const int r = idx & 262143;
        const int k = r >> 9, n = r & 511;
        const float* src = ((seg == 0) ? wq : (seg == 1) ? wk : (seg == 2) ? wv : wo)
                           + (long)layer * 262144;
        const float x = src[r];
        const bf h = __float2bfloat16(x);
        const bf l = __float2bfloat16(x - __bfloat162float(h));
        if (seg < 3) {
            const long o = (long)(seg * 512 + n) * 512 + k;
            if (layer == 0) { qkvTh0[o] = h; qkvTl0[o] = l; }
            else            { qkvTh1[o] = h; qkvTl1[o] = l; }
        } else {
            const long o = (long)n * 512 + k;
            if (layer == 0) { woTh0[o] = h; woTl0[o] = l; }
            else            { woTh1[o] = h; woTl1[o] = l; }
        }
    } else if (idx < 2162688) {     // wz: 512x128 split-T
        const int i = idx - 2097152;
        const int k = i >> 7, n = i & 127;
        const float x = wz[i];
        const bf h = __float2bfloat16(x);
        wzTh[(long)n * 512 + k] = h;
        wzTl[(long)n * 512 + k] = __float2bfloat16(x - __bfloat162float(h));
    } else if (idx < 2228224) {     // w1: 64x1024 plain-T
        const int i = idx - 2162688;
        const int k = i >> 10, n = i & 1023;
        w1T[(long)n * 64 + k] = __float2bfloat16(w1[i]);
    } else if (idx < 3276800) {     // w2: 1024x1024 plain-T
        const int i = idx - 2228224;
        const int k = i >> 10, n = i & 1023;
        w2T[(long)n * 1024 + k] = __float2bfloat16(w2[i]);
    } else if (idx < 3801088) {     // w3: 1024x512 plain-T
        const int i = idx - 3276800;
        const int k = i >> 9, n = i & 511;
        w3T[(long)n * 1024 + k] = __float2bfloat16(w3[i]);
    } else if (idx < 3903488) {     // zero EM musum buffers 1..5
        msP[20480 + (idx - 3801088)] = 0.f;
    } else if (idx < 3905088) {     // zero EM Nk buffers 1..5
        nkP[320 + (idx - 3903488)] = 0.f;
    }
}

// ---------------------------------------------------------------------------
__global__ __launch_bounds__(256)
void zgen(const float* __restrict__ stats, const float* __restrict__ eps,
          float* __restrict__ z, bf* __restrict__ z16)
{
    const int idx = blockIdx.x * 256 + threadIdx.x;
    const int bs = idx / 160;
    const int r = idx % 160;
    const int l4 = r % 16;
    const float4 e = ((const float4*)eps)[idx];
    const float4 mn = ((const float4*)stats)[bs * 32 + l4];
    const float4 lv = ((const float4*)stats)[bs * 32 + 16 + l4];
    float4 zz;
    zz.x = fmaf(e.x, expf(0.5f * lv.x), mn.x);
    zz.y = fmaf(e.y, expf(0.5f * lv.y), mn.y);
    zz.z = fmaf(e.z, expf(0.5f * lv.z), mn.z);
    zz.w = fmaf(e.w, expf(0.5f * lv.w), mn.w);
    ((float4*)z)[idx] = zz;
    bf* zp = z16 + (long)idx * 4;
    zp[0] = __float2bfloat16(zz.x);
    zp[1] = __float2bfloat16(zz.y);
    zp[2] = __float2bfloat16(zz.z);
    zp[3] = __float2bfloat16(zz.w);
}

// ---------------------------------------------------------------------------
// EM init: seed ping-pong buffer 0 with musum = gathered z, Nk = 1
// (so mu = musum/Nk = z_gather and logPi = log(1/K) in the first E-step).
// ---------------------------------------------------------------------------
__global__ void em_init(const float* __restrict__ z, const int* __restrict__ init_idx,
                        float* __restrict__ ms0, float* __restrict__ nk0)
{
    const int b = blockIdx.x, t = threadIdx.x;
    for (int i = t; i < KC * LD; i += 256) {
        const int k = i >> 6, l = i & 63;
        const int idx = init_idx[b * KC + k];
        ms0[b * KC * LD + i] = z[((long)b * NPTS + idx) * LD + l];
    }
    if (t < KC) nk0[b * KC + t] = 1.f;
}

// ---------------------------------------------------------------------------
// Fused E-step with folded M-step: reads (msIn, nkIn) -> mu, logPi computed
// per block; posteriors; accumulates into (msOut, nkOut) (pre-zeroed).
// grid (10, 16) x 256.
// ---------------------------------------------------------------------------
__global__ __launch_bounds__(256)
void em_step(const float* __restrict__ z,
             const float* __restrict__ msIn, const float* __restrict__ nkIn,
             float* __restrict__ msOut, float* __restrict__ nkOut)
{
    __shared__ float muS[KC][65];
    __shared__ float m2lp[KC];
    __shared__ float NkU[KC];
    __shared__ float postS[KC][256];
    __shared__ float NkS[KC];

    const int tile = blockIdx.x, b = blockIdx.y, t = threadIdx.x;
    const int lane = t & 63, w = t >> 6;

    if (t < KC) NkU[t] = nkIn[b * KC + t];
    __syncthreads();
    for (int i = t; i < KC * LD; i += 256)
        muS[i >> 6][i & 63] = msIn[b * KC * LD + i] / NkU[i >> 6];
    __syncthreads();
    if (t < KC) {
        float s = 0.f;
        for (int l = 0; l < LD; l++) { const float m = muS[t][l]; s = fmaf(m, m, s); }
        float sn = 0.f;
        for (int k = 0; k < KC; k++) sn += NkU[k];
        m2lp[t] = -0.5f * s + logf(NkU[t] / sn);
    }
    __syncthreads();

    const long n = (long)tile * 256 + t;
    const float* zr = &z[((long)b * NPTS + n) * LD];
    float acc[KC];
#pragma unroll
    for (int k = 0; k < KC; k++) acc[k] = 0.f;
#pragma unroll
    for (int l4 = 0; l4 < 16; l4++) {
        const float4 zv = ((const float4*)zr)[l4];
#pragma unroll
        for (int k = 0; k < KC; k++) {
            acc[k] = fmaf(zv.x, muS[k][l4 * 4 + 0], acc[k]);
            acc[k] = fmaf(zv.y, muS[k][l4 * 4 + 1], acc[k]);
            acc[k] = fmaf(zv.z, muS[k][l4 * 4 + 2], acc[k]);
            acc[k] = fmaf(zv.w, muS[k][l4 * 4 + 3], acc[k]);
        }
    }
    float mx = -1e30f;
    float llv[KC];
#pragma unroll
    for (int k = 0; k < KC; k++) { llv[k] = acc[k] + m2lp[k]; mx = fmaxf(mx, llv[k]); }
    float s = 0.f;
#pragma unroll
    for (int k = 0; k < KC; k++) { llv[k] = expf(llv[k] - mx); s += llv[k]; }
    const float inv = 1.f / s;
#pragma unroll
    for (int k = 0; k < KC; k++) postS[k][t] = llv[k] * inv;
    __syncthreads();

#pragma unroll
    for (int kk = 0; kk < 5; kk++) {
        const int k = w * 5 + kk;
        float p = postS[k][lane] + postS[k][lane + 64] + postS[k][lane + 128] + postS[k][lane + 192];
        p = warpReduceSum(p);
        if (lane == 0) NkS[k] = p;
    }
    __syncthreads();

    const float* zb = &z[((long)b * NPTS + (long)tile * 256) * LD];
#pragma unroll
    for (int j = 0; j < 5; j++) {
        const int o = t + j * 256;
        const int k = o >> 6, l = o & 63;
        float sacc = 0.f;
        for (int n2 = 0; n2 < 256; n2++)
            sacc = fmaf(postS[k][n2], zb[n2 * LD + l], sacc);
        atomicAdd(&msOut[b * KC * LD + o], sacc);
    }
    if (t < KC) atomicAdd(&nkOut[b * KC + t], NkS[t]);
}

// ---------------------------------------------------------------------------
// KL with folded final M-step: reads buffer 5 -> mu, logPi per block.
// ---------------------------------------------------------------------------
__global__ __launch_bounds__(256)
void kl_kernel(const float* __restrict__ z, const float* __restrict__ stats,
               const float* __restrict__ eps,
               const float* __restrict__ msIn, const float* __restrict__ nkIn,
               float* __restrict__ klAcc)
{
    __shared__ float muS[KC][65];
    __shared__ float m2lp[KC];
    __shared__ float NkU[KC];
    __shared__ float redS[4];

    const int tile = blockIdx.x, b = blockIdx.y, t = threadIdx.x;

    if (t < KC) NkU[t] = nkIn[b * KC + t];
    __syncthreads();
    for (int i = t; i < KC * LD; i += 256)
        muS[i >> 6][i & 63] = msIn[b * KC * LD + i] / NkU[i >> 6];
    __syncthreads();
    if (t < KC) {
        float s = 0.f;
        for (int l = 0; l < LD; l++) { const float m = muS[t][l]; s = fmaf(m, m, s); }
        float sn = 0.f;
        for (int k = 0; k < KC; k++) sn += NkU[k];
        m2lp[t] = -0.5f * s + logf(NkU[t] / sn);
    }
    __syncthreads();

    const int n = tile * 256 + t;
    const int sidx = n / MC, m = n % MC;
    const long bs = (long)b * SEQ + sidx;
    const float* zr = &z[((long)b * NPTS + n) * LD];

    float acc[KC];
#pragma unroll
    for (int k = 0; k < KC; k++) acc[k] = 0.f;
    float x2 = 0.f;
#pragma unroll
    for (int l4 = 0; l4 < 16; l4++) {
        const float4 zv = ((const float4*)zr)[l4];
        x2 = fmaf(zv.x, zv.x, fmaf(zv.y, zv.y, fmaf(zv.z, zv.z, fmaf(zv.w, zv.w, x2))));
#pragma unroll
        for (int k = 0; k < KC; k++) {
            acc[k] = fmaf(zv.x, muS[k][l4 * 4 + 0], acc[k]);
            acc[k] = fmaf(zv.y, muS[k][l4 * 4 + 1], acc[k]);
            acc[k] = fmaf(zv.z, muS[k][l4 * 4 + 2], acc[k]);
            acc[k] = fmaf(zv.w, muS[k][l4 * 4 + 3], acc[k]);
        }
    }
    float mx = -1e30f;
    float llv[KC];
#pragma unroll
    for (int k = 0; k < KC; k++) { llv[k] = acc[k] + m2lp[k]; mx = fmaxf(mx, llv[k]); }
    float s = 0.f;
#pragma unroll
    for (int k = 0; k < KC; k++) s += expf(llv[k] - mx);
    const float log_pz = -0.5f * x2 + mx + logf(s) + LD * LOG_NORM;

    const float* lvr = &stats[bs * 128 + 64];
    const float* er = &eps[(bs * MC + m) * LD];
    float slv = 0.f, se2 = 0.f;
#pragma unroll
    for (int l4 = 0; l4 < 16; l4++) {
        const float4 lv = ((const float4*)lvr)[l4];
        slv += lv.x + lv.y + lv.z + lv.w;
        const float4 e = ((const float4*)er)[l4];
        se2 = fmaf(e.x, e.x, fmaf(e.y, e.y, fmaf(e.z, e.z, fmaf(e.w, e.w, se2))));
    }
    const float log_qz = -0.5f * (slv + se2) + LD * LOG_NORM;

    float v = log_qz - log_pz;
    v = warpReduceSum(v);
    if ((t & 63) == 0) redS[t >> 6] = v;
    __syncthreads();
    if (t == 0) atomicAdd(klAcc, redS[0] + redS[1] + redS[2] + redS[3]);
}

__global__ void finalize(const float* __restrict__ scal, float* __restrict__ out)
{
    if (threadIdx.x == 0) {
        out[0] = scal[0] * (1.f / (float)NROWS);
        out[1] = scal[1] * (1.f / (float)NROWS);
    }
}

// ---------------------------------------------------------------------------
extern "C" void kernel_launch(void* const* d_in, const int* in_sizes, int n_in,
                              void* d_out, int out_size, void* d_ws, size_t ws_size,
                              hipStream_t stream)
{
    const float* H   = (const float*)d_in[0];
    const float* eps = (const float*)d_in[1];
    const float* wq  = (const float*)d_in[2];
    const float* bq  = (const float*)d_in[3];
    const float* wk  = (const float*)d_in[4];
    const float* bk  = (const float*)d_in[5];
    const float* wv  = (const float*)d_in[6];
    const float* bv  = (const float*)d_in[7];
    const float* wo  = (const float*)d_in[8];
    const float* bo  = (const float*)d_in[9];
    const float* wz  = (const float*)d_in[10];
    const float* bz  = (const float*)d_in[11];
    const float* w1  = (const float*)d_in[12];
    const float* b1  = (const float*)d_in[13];
    const float* w2  = (const float*)d_in[14];
    const float* b2  = (const float*)d_in[15];
    const float* w3  = (const float*)d_in[16];
    const float* b3  = (const float*)d_in[17];
    const int* init_idx = (const int*)d_in[18];
    float* out = (float*)d_out;
    float* wsf = (float*)d_ws;

    // ---- workspace layout (float slots), ws = 256 MiB, used ~240 MB ----
    const long o_scal  = 0;          // 16
    const long o_nk    = 1024;       // 6 x 16 x 20 = 1920
    const long o_ms    = 4096;       // 6 x 16 x 1280 = 122880 -> 126976
    const long o_st    = 131072;     // 524288 -> 655360
    const long o_zb    = 655360;     // 2621440 -> 3276800
    const long o_z16   = 3276800;    // 1310720 -> 4587520
    const long o_q     = 4587520;
    const long o_k     = 6684672;
    const long o_vT    = 8781824;
    const long o_o     = 10878976;
    const long o_h1    = 12976128;
    const long o_qkvT0 = 15073280;
    const long o_woT0  = 15859712;
    const long o_qkvT1 = 16121856;
    const long o_woT1  = 16908288;
    const long o_wzT   = 17170432;
    const long o_w1T   = 17235968;
    const long o_w2T   = 17268736;
    const long o_w3T   = 17793024;
    const long o_d1    = 18055168;   // 20971520
    const long o_d2    = 39026688;   // 20971520 -> ends 59998208 (240 MB)

    const long PL = (long)BS_TOT * DIM;
    bf* qh  = (bf*)(wsf + o_q);   bf* ql  = qh + PL;
    bf* kh  = (bf*)(wsf + o_k);   bf* kl_ = kh + PL;
    bf* vTh = (bf*)(wsf + o_vT);  bf* vTl = vTh + PL;
    bf* oh  = (bf*)(wsf + o_o);   bf* ol  = oh + PL;
    bf* h1h = (bf*)(wsf + o_h1);  bf* h1l = h1h + PL;
    bf* h2h = qh;                 bf* h2l = ql;
    bf* qkvTh0 = (bf*)(wsf + o_qkvT0); bf* qkvTl0 = qkvTh0 + 1536L * 512;
    bf* woTh0  = (bf*)(wsf + o_woT0);  bf* woTl0  = woTh0 + 512L * 512;
    bf* qkvTh1 = (bf*)(wsf + o_qkvT1); bf* qkvTl1 = qkvTh1 + 1536L * 512;
    bf* woTh1  = (bf*)(wsf + o_woT1);  bf* woTl1  = woTh1 + 512L * 512;
    bf* wzTh = (bf*)(wsf + o_wzT);     bf* wzTl = wzTh + 128L * 512;
    bf* w1T = (bf*)(wsf + o_w1T);
    bf* w2T = (bf*)(wsf + o_w2T);
    bf* w3T = (bf*)(wsf + o_w3T);
    bf* z16 = (bf*)(wsf + o_z16);
    bf* d1  = (bf*)(wsf + o_d1);
    bf* d2  = (bf*)(wsf + o_d2);
    float* st = wsf + o_st;
    float* zb = wsf + o_zb;
    float* scal = wsf + o_scal;
    float* msP = wsf + o_ms;    // [6][16][20][64] ping-pong musum buffers
    float* nkP = wsf + o_nk;    // [6][16][20]     ping-pong Nk buffers

    const dim3 blk(256);

    // ---- all conversions + scal zero + EM buffer zero, one launch ----
    conv_all<<<23447, blk, 0, stream>>>(
        H, h1h, h1l,
        wq, wk, wv, wo,
        qkvTh0, qkvTl0, woTh0, woTl0,
        qkvTh1, qkvTl1, woTh1, woTl1,
        wz, wzTh, wzTl, w1, w1T, w2, w2T, w3, w3T,
        scal, msP, nkP);

    // ---- 2x MAB on split-bf16 MFMA ----
    for (int i = 0; i < 2; i++) {
        const long boff = (long)i * DIM;
        bf* qkh = i ? qkvTh1 : qkvTh0;  bf* qkl = i ? qkvTl1 : qkvTl0;
        bf* wh  = i ? woTh1 : woTh0;    bf* wl  = i ? woTl1 : woTl0;

        gemm3t<0><<<dim3(12, 64), blk, 0, stream>>>(
            h1h, h1l, qkh, qkl, 512, 512, 512,
            bq + boff, bk + boff, bv + boff, nullptr,
            qh, ql, kh, kl_, vTh, vTl, nullptr, nullptr);
        attn_fused<<<dim3(4, 64), blk, 0, stream>>>(qh, ql, kh, kl_, vTh, vTl, oh, ol);
        bf* houth = (i == 0) ? h1h : h2h;
        bf* houtl = (i == 0) ? h1l : h2l;
        gemm3t<3><<<dim3(4, 64), blk, 0, stream>>>(
            oh, ol, wh, wl, 512, 512, 512,
            bo + boff, nullptr, nullptr, nullptr,
            houth, houtl, nullptr, nullptr, nullptr, nullptr, oh, ol);
    }

    // ---- stats = h2 @ wz + bz ----
    gemm3t<4><<<dim3(1, 64), blk, 0, stream>>>(
        h2h, h2l, wzTh, wzTl, 512, 512, 512,
        bz, nullptr, nullptr, st,
        nullptr, nullptr, nullptr, nullptr, nullptr, nullptr, nullptr, nullptr);

    // ---- z (fp32 exact + bf16 copy) ----
    zgen<<<2560, blk, 0, stream>>>(st, eps, zb, z16);

    // ---- decoder MLP + fused rec_loss (needs only z16) ----
    gemm_mfma<false><<<dim3(8, 320), blk, 0, stream>>>(
        z16, w1T, d1, b1, nullptr, nullptr, 64, 1024);
    gemm_mfma<false><<<dim3(8, 320), blk, 0, stream>>>(
        d1, w2T, d2, b2, nullptr, nullptr, 1024, 1024);
    gemm_mfma<true><<<dim3(4, 320), blk, 0, stream>>>(
        d2, w3T, nullptr, b3, H, scal + 0, 1024, 512);

    // ---- EM: init buffer0, 5 ping-pong fused E+M steps, KL off buffer5 ----
    em_init<<<16, blk, 0, stream>>>(zb, init_idx, msP, nkP);
    for (int it = 0; it < 5; it++) {
        em_step<<<dim3(10, 16), blk, 0, stream>>>(
            zb,
            msP + (long)it * 16 * KC * LD, nkP + (long)it * 16 * KC,
            msP + (long)(it + 1) * 16 * KC * LD, nkP + (long)(it + 1) * 16 * KC);
    }
    kl_kernel<<<dim3(10, 16), blk, 0, stream>>>(
        zb, st, eps,
        msP + 5L * 16 * KC * LD, nkP + 5L * 16 * KC, scal + 1);

    finalize<<<1, 64, 0, stream>>>(scal, out);
}

// Round 10
// 668.782 us; speedup vs baseline: 2.1729x; 1.0380x over previous
//
#include <hip/hip_runtime.h>
#include <hip/hip_bf16.h>
#include <math.h>

// ---------------------------------------------------------------------------
// GMVAE fused pipeline. Round 10: K-unroll x2 with dual LDS staging buffers
// in gemm_mfma and gemm3t — one barrier pair per 64-K (32 MFMAs/barrier-pair,
// AITER-level density) while keeping the conflict-optimal [.][32] layout.
// EM ping-pong (round 9, verified). Accumulation order unchanged -> absmax 0.
// ---------------------------------------------------------------------------

#define BATCH 16
#define SEQ 256
#define DIM 512
#define NH 4
#define DH 128
#define LD 64
#define KC 20
#define MC 10
#define NPTS 2560
#define BS_TOT 4096
#define NROWS 40960
#define LOG_NORM (-0.9189385332046727f)

typedef __attribute__((ext_vector_type(8))) short bf16x8;
typedef __attribute__((ext_vector_type(4))) float f32x4;
typedef __hip_bfloat16 bf;

__device__ inline float warpReduceSum(float v) {
    for (int o = 32; o > 0; o >>= 1) v += __shfl_down(v, o);
    return v;
}

__device__ inline void async_copy16(const bf* g, bf* l) {
    __builtin_amdgcn_global_load_lds(
        (const __attribute__((address_space(1))) unsigned int*)g,
        (__attribute__((address_space(3))) unsigned int*)l, 16, 0, 0);
}

__device__ inline void split_store(float x, bf* ph, bf* pl, long idx) {
    const bf h = __float2bfloat16(x);
    ph[idx] = h;
    pl[idx] = __float2bfloat16(x - __bfloat162float(h));
}

// ---------------------------------------------------------------------------
// Split-bf16 MFMA GEMM, 64x128 tile, BK=32 staged, K-unrolled x2 (two buffer
// sets, one barrier pair per 64-K). 4 waves x (4x2 MFMAs x 3 split groups)
// per 32-K tile. K must be a multiple of 64 (512 here).
// MODE: 0=QKV(fused q/k/vT out) 3=OPROJ(bias,relu,+resid) 4=STATS(fp32+bias)
// ---------------------------------------------------------------------------
template<int MODE>
__global__ __launch_bounds__(256, 3)
void gemm3t(const bf* __restrict__ Ah, const bf* __restrict__ Al,
            const bf* __restrict__ Bh, const bf* __restrict__ Bl,
            int K, int lda, int ldb,
            const float* __restrict__ b0, const float* __restrict__ b1v,
            const float* __restrict__ b2v,
            float* __restrict__ outF,
            bf* __restrict__ P1h, bf* __restrict__ P1l,
            bf* __restrict__ P2h, bf* __restrict__ P2l,
            bf* __restrict__ P3h, bf* __restrict__ P3l,
            const bf* __restrict__ Rh, const bf* __restrict__ Rl)
{
    // two 24 KB buffer sets
    __shared__ __align__(16) char smem[49152];
    float* Xs = (float*)smem;        // epilogue overlay [64][68] = 17408 B

    const int t = threadIdx.x;
    const int m0 = blockIdx.y * 64, n0 = blockIdx.x * 128;
    const int w = t >> 6, lane = t & 63;
    const int wn = w * 32;
    const int fm = lane & 15, quad = lane >> 4, fk = quad * 8;
    const int srow = t >> 2, scol = (t & 3) * 8;

    f32x4 acc[4][2];
#pragma unroll
    for (int i = 0; i < 4; i++)
#pragma unroll
        for (int j = 0; j < 2; j++) acc[i][j] = (f32x4){0.f, 0.f, 0.f, 0.f};

    const int nk2 = K >> 6;
    for (int kk2 = 0; kk2 < nk2; kk2++) {
#pragma unroll
        for (int h = 0; h < 2; h++) {
            const int kk = kk2 * 2 + h;
            char* base = smem + h * 24576;
            bf* Ash = (bf*)base;
            bf* Asl = (bf*)(base + 4096);
            bf* Bsh = (bf*)(base + 8192);
            bf* Bsl = (bf*)(base + 16384);
            const long ao = (long)(m0 + srow) * lda + kk * 32 + scol;
            const long bo = (long)(n0 + srow) * ldb + kk * 32 + scol;
            async_copy16(Ah + ao, Ash + w * 512);
            async_copy16(Al + ao, Asl + w * 512);
            async_copy16(Bh + bo, Bsh + w * 512);
            async_copy16(Bh + bo + 64L * ldb, Bsh + 2048 + w * 512);
            async_copy16(Bl + bo, Bsl + w * 512);
            async_copy16(Bl + bo + 64L * ldb, Bsl + 2048 + w * 512);
        }
        __syncthreads();

#pragma unroll
        for (int h = 0; h < 2; h++) {
            char* base = smem + h * 24576;
            bf* Ash = (bf*)base;
            bf* Asl = (bf*)(base + 4096);
            bf* Bsh = (bf*)(base + 8192);
            bf* Bsl = (bf*)(base + 16384);
            bf16x8 afh[4], afl[4], bfh[2], bfl[2];
#pragma unroll
            for (int mi = 0; mi < 4; mi++) {
                afh[mi] = *(const bf16x8*)&Ash[(mi * 16 + fm) * 32 + fk];
                afl[mi] = *(const bf16x8*)&Asl[(mi * 16 + fm) * 32 + fk];
            }
#pragma unroll
            for (int ni = 0; ni < 2; ni++) {
                bfh[ni] = *(const bf16x8*)&Bsh[(wn + ni * 16 + fm) * 32 + fk];
                bfl[ni] = *(const bf16x8*)&Bsl[(wn + ni * 16 + fm) * 32 + fk];
            }
#pragma unroll
            for (int mi = 0; mi < 4; mi++)
#pragma unroll
                for (int ni = 0; ni < 2; ni++) {
                    acc[mi][ni] = __builtin_amdgcn_mfma_f32_16x16x32_bf16(
                        afh[mi], bfh[ni], acc[mi][ni], 0, 0, 0);
                    acc[mi][ni] = __builtin_amdgcn_mfma_f32_16x16x32_bf16(
                        afh[mi], bfl[ni], acc[mi][ni], 0, 0, 0);
                    acc[mi][ni] = __builtin_amdgcn_mfma_f32_16x16x32_bf16(
                        afl[mi], bfh[ni], acc[mi][ni], 0, 0, 0);
                }
        }
        __syncthreads();
    }

    // ---- epilogue: two 64-col half-passes through LDS fp32 staging ----
    const int rl = t >> 2;
    const int cc4 = (t & 3) * 16;

    for (int p = 0; p < 2; p++) {
        if ((w >> 1) == p) {
            const int cb = wn - p * 64;
#pragma unroll
            for (int mi = 0; mi < 4; mi++)
#pragma unroll
                for (int ni = 0; ni < 2; ni++) {
                    const int c = cb + ni * 16 + fm;
#pragma unroll
                    for (int r = 0; r < 4; r++)
                        Xs[(mi * 16 + quad * 4 + r) * 68 + c] = acc[mi][ni][r];
                }
        }
        __syncthreads();

        if (MODE == 0 && n0 >= 1024) {
            const int hh = (n0 >> 7) & 3;
            const int dd = p * 64 + rl;
            const int bb = m0 >> 8;
            const int sb = (m0 & 255) + cc4;
            const float bias = b2v[hh * 128 + dd];
            const long ob = (((long)(bb * NH + hh) * DH + dd) << 8) + sb;
#pragma unroll
            for (int j = 0; j < 2; j++) {
                bf16x8 vh, vl;
#pragma unroll
                for (int i = 0; i < 8; i++) {
                    const float x = Xs[(cc4 + j * 8 + i) * 68 + rl] + bias;
                    const bf h = __float2bfloat16(x);
                    vh[i] = *(const short*)&h;
                    const bf l = __float2bfloat16(x - __bfloat162float(h));
                    vl[i] = *(const short*)&l;
                }
                *(bf16x8*)&P3h[ob + j * 8] = vh;
                *(bf16x8*)&P3l[ob + j * 8] = vl;
            }
        } else {
            float xv[16];
#pragma unroll
            for (int i = 0; i < 4; i++)
                *(float4*)&xv[i * 4] = *(const float4*)&Xs[rl * 68 + cc4 + i * 4];

            if (MODE == 0) {
                const int which = n0 >> 9;
                const int colq = (n0 & 511) + p * 64 + cc4;
                const float* bias = which ? b1v : b0;
                bf* Ph = which ? P2h : P1h;
                bf* Pl = which ? P2l : P1l;
                const long ob = (long)(m0 + rl) * 512 + colq;
#pragma unroll
                for (int j = 0; j < 2; j++) {
                    bf16x8 vh, vl;
#pragma unroll
                    for (int i = 0; i < 8; i++) {
                        const float x = xv[j * 8 + i] + bias[colq + j * 8 + i];
                        const bf h = __float2bfloat16(x); vh[i] = *(const short*)&h;
                        const bf l = __float2bfloat16(x - __bfloat162float(h));
                        vl[i] = *(const short*)&l;
                    }
                    *(bf16x8*)&Ph[ob + j * 8] = vh;
                    *(bf16x8*)&Pl[ob + j * 8] = vl;
                }
            } else if (MODE == 3) {
                const int colg = n0 + p * 64 + cc4;
                const long ob = (long)(m0 + rl) * 512 + colg;
#pragma unroll
                for (int j = 0; j < 2; j++) {
                    const bf16x8 rh = *(const bf16x8*)&Rh[ob + j * 8];
                    const bf16x8 rv = *(const bf16x8*)&Rl[ob + j * 8];
                    bf16x8 vh, vl;
#pragma unroll
                    for (int i = 0; i < 8; i++) {
                        short sh = rh[i], sl = rv[i];
                        float x = fmaxf(xv[j * 8 + i] + b0[colg + j * 8 + i], 0.f)
                                + __bfloat162float(*(const bf*)&sh)
                                + __bfloat162float(*(const bf*)&sl);
                        const bf h = __float2bfloat16(x); vh[i] = *(const short*)&h;
                        const bf l = __float2bfloat16(x - __bfloat162float(h));
                        vl[i] = *(const short*)&l;
                    }
                    *(bf16x8*)&P1h[ob + j * 8] = vh;
                    *(bf16x8*)&P1l[ob + j * 8] = vl;
                }
            } else {
                const int colg = p * 64 + cc4;
                const long ob = (long)(m0 + rl) * 128 + colg;
#pragma unroll
                for (int i = 0; i < 4; i++) {
                    float4 v = *(float4*)&xv[i * 4];
                    v.x += b0[colg + i * 4 + 0];
                    v.y += b0[colg + i * 4 + 1];
                    v.z += b0[colg + i * 4 + 2];
                    v.w += b0[colg + i * 4 + 3];
                    *(float4*)&outF[ob + i * 4] = v;
                }
            }
        }
        __syncthreads();
    }
}

// ---------------------------------------------------------------------------
// Fused attention (unchanged, verified).
// ---------------------------------------------------------------------------
__global__ __launch_bounds__(256)
void attn_fused(const bf* __restrict__ qh, const bf* __restrict__ ql,
                const bf* __restrict__ kh, const bf* __restrict__ kl,
                const bf* __restrict__ vTh, const bf* __restrict__ vTl,
                bf* __restrict__ oh, bf* __restrict__ ol)
{
    __shared__ __align__(16) char smem[43008];
    bf* Qsh = (bf*)smem;            bf* Qsl = (bf*)(smem + 4096);
    bf* Ksh = (bf*)(smem + 8192);   bf* Ksl = (bf*)(smem + 24576);
    bf* Psh = (bf*)smem;            bf* Psl = (bf*)(smem + 4096);
    bf* Vsh = (bf*)(smem + 8192);   bf* Vsl = (bf*)(smem + 16384);
    float (*red)[4]  = (float(*)[4])(smem + 40960);
    float (*red2)[4] = (float(*)[4])(smem + 41984);

    const int t = threadIdx.x;
    const int z = blockIdx.y;
    const int m0 = blockIdx.x * 64;
    const int bb = z >> 2, hh = z & 3;
    const long hOff = (long)bb * 131072 + (long)hh * 128;
    const long vOff = (long)z * 32768;

    const int w = t >> 6, lane = t & 63;
    const int fm = lane & 15;
    const int quad = lane >> 4;
    const int fk = quad * 8;
    const int srow = t >> 2, scol = (t & 3) * 8;

    f32x4 acc[4][4];
#pragma unroll
    for (int i = 0; i < 4; i++)
#pragma unroll
        for (int j = 0; j < 4; j++) acc[i][j] = (f32x4){0.f, 0.f, 0.f, 0.f};

    for (int kk = 0; kk < 4; kk++) {
        const long ao = hOff + (long)(m0 + srow) * 512 + kk * 32 + scol;
        const long bo = hOff + (long)srow * 512 + kk * 32 + scol;
        async_copy16(qh + ao, Qsh + w * 512);
        async_copy16(ql + ao, Qsl + w * 512);
#pragma unroll
        for (int j = 0; j < 4; j++) {
            async_copy16(kh + bo + (long)j * 64 * 512, Ksh + w * 512 + j * 2048);
            async_copy16(kl + bo + (long)j * 64 * 512, Ksl + w * 512 + j * 2048);
        }
        __syncthreads();

        bf16x8 afh[4], afl[4];
#pragma unroll
        for (int mi = 0; mi < 4; mi++) {
            afh[mi] = *(const bf16x8*)&Qsh[(mi * 16 + fm) * 32 + fk];
            afl[mi] = *(const bf16x8*)&Qsl[(mi * 16 + fm) * 32 + fk];
        }
#pragma unroll
        for (int ni = 0; ni < 4; ni++) {
            const bf16x8 bh = *(const bf16x8*)&Ksh[(w * 64 + ni * 16 + fm) * 32 + fk];
            const bf16x8 bl = *(const bf16x8*)&Ksl[(w * 64 + ni * 16 + fm) * 32 + fk];
#pragma unroll
            for (int mi = 0; mi < 4; mi++) {
                acc[mi][ni] = __builtin_amdgcn_mfma_f32_16x16x32_bf16(
                    afh[mi], bh, acc[mi][ni], 0, 0, 0);
                acc[mi][ni] = __builtin_amdgcn_mfma_f32_16x16x32_bf16(
                    afh[mi], bl, acc[mi][ni], 0, 0, 0);
                acc[mi][ni] = __builtin_amdgcn_mfma_f32_16x16x32_bf16(
                    afl[mi], bh, acc[mi][ni], 0, 0, 0);
            }
        }
        __syncthreads();
    }

    const float alpha = 0.044194173824159216f;
#pragma unroll
    for (int mi = 0; mi < 4; mi++)
#pragma unroll
        for (int r = 0; r < 4; r++) {
            float m = -1e30f;
#pragma unroll
            for (int ni = 0; ni < 4; ni++) m = fmaxf(m, acc[mi][ni][r]);
            for (int o = 8; o > 0; o >>= 1) m = fmaxf(m, __shfl_xor(m, o));
            if (fm == 0) red[mi * 16 + quad * 4 + r][w] = m;
        }
    __syncthreads();
    float invr[4][4];
#pragma unroll
    for (int mi = 0; mi < 4; mi++)
#pragma unroll
        for (int r = 0; r < 4; r++) {
            const int rowl = mi * 16 + quad * 4 + r;
            const float mx = fmaxf(fmaxf(red[rowl][0], red[rowl][1]),
                                   fmaxf(red[rowl][2], red[rowl][3]));
            float s = 0.f;
#pragma unroll
            for (int ni = 0; ni < 4; ni++) {
                const float e = __expf((acc[mi][ni][r] - mx) * alpha);
                acc[mi][ni][r] = e;
                s += e;
            }
            for (int o = 8; o > 0; o >>= 1) s += __shfl_xor(s, o);
            if (fm == 0) red2[rowl][w] = s;
        }
    __syncthreads();
#pragma unroll
    for (int mi = 0; mi < 4; mi++)
#pragma unroll
        for (int r = 0; r < 4; r++) {
            const int rowl = mi * 16 + quad * 4 + r;
            invr[mi][r] = 1.f / (red2[rowl][0] + red2[rowl][1] + red2[rowl][2] + red2[rowl][3]);
        }

    f32x4 acc2[4][2];
#pragma unroll
    for (int i = 0; i < 4; i++)
#pragma unroll
        for (int j = 0; j < 2; j++) acc2[i][j] = (f32x4){0.f, 0.f, 0.f, 0.f};

    for (int kc = 0; kc < 8; kc++) {
        if (w == (kc >> 1)) {
            const int nib = (kc & 1) * 2;
#pragma unroll
            for (int mi = 0; mi < 4; mi++)
#pragma unroll
                for (int r = 0; r < 4; r++) {
                    const int row = mi * 16 + quad * 4 + r;
#pragma unroll
                    for (int j = 0; j < 2; j++) {
                        const float p = acc[mi][nib + j][r] * invr[mi][r];
                        const int cc = j * 16 + fm;
                        const bf h = __float2bfloat16(p);
                        Psh[row * 32 + cc] = h;
                        Psl[row * 32 + cc] = __float2bfloat16(p - __bfloat162float(h));
                    }
                }
        }
        const long vo = vOff + (long)srow * 256 + kc * 32 + scol;
        async_copy16(vTh + vo, Vsh + w * 512);
        async_copy16(vTh + vo + 64L * 256, Vsh + w * 512 + 2048);
        async_copy16(vTl + vo, Vsl + w * 512);
        async_copy16(vTl + vo + 64L * 256, Vsl + w * 512 + 2048);
        __syncthreads();

        bf16x8 pfh[4], pfl[4];
#pragma unroll
        for (int mi = 0; mi < 4; mi++) {
            pfh[mi] = *(const bf16x8*)&Psh[(mi * 16 + fm) * 32 + fk];
            pfl[mi] = *(const bf16x8*)&Psl[(mi * 16 + fm) * 32 + fk];
        }
#pragma unroll
        for (int ni = 0; ni < 2; ni++) {
            const bf16x8 vh = *(const bf16x8*)&Vsh[(w * 32 + ni * 16 + fm) * 32 + fk];
            const bf16x8 vl = *(const bf16x8*)&Vsl[(w * 32 + ni * 16 + fm) * 32 + fk];
#pragma unroll
            for (int mi = 0; mi < 4; mi++) {
                acc2[mi][ni] = __builtin_amdgcn_mfma_f32_16x16x32_bf16(
                    pfh[mi], vh, acc2[mi][ni], 0, 0, 0);
                acc2[mi][ni] = __builtin_amdgcn_mfma_f32_16x16x32_bf16(
                    pfh[mi], vl, acc2[mi][ni], 0, 0, 0);
                acc2[mi][ni] = __builtin_amdgcn_mfma_f32_16x16x32_bf16(
                    pfl[mi], vh, acc2[mi][ni], 0, 0, 0);
            }
        }
        __syncthreads();
    }

#pragma unroll
    for (int ni = 0; ni < 2; ni++) {
        const int col = hh * 128 + w * 32 + ni * 16 + fm;
#pragma unroll
        for (int mi = 0; mi < 4; mi++)
#pragma unroll
            for (int r = 0; r < 4; r++) {
                const int row = mi * 16 + quad * 4 + r;
                const long idx = (long)(bb * 256 + m0 + row) * 512 + col;
                const float x = acc2[mi][ni][r]
                    + __bfloat162float(qh[idx]) + __bfloat162float(ql[idx]);
                split_store(x, oh, ol, idx);
            }
    }
}

// ---------------------------------------------------------------------------
// plain-bf16 decoder GEMM, single dispatch, XCD swizzle, K-unrolled x2.
// K must be a multiple of 64 (64, 1024 here).
// ---------------------------------------------------------------------------
template<bool SQLOSS>
__global__ __launch_bounds__(256, 3)
void gemm_mfma(const bf* __restrict__ A, const bf* __restrict__ BT,
               bf* __restrict__ C,
               const float* __restrict__ bias,
               const float* __restrict__ Href,
               float* __restrict__ lossAcc,
               int K, int N)
{
    // two 16 KB buffer sets (A+B each 8 KB)
    __shared__ __align__(16) char smem[32768];
    bf* Cs  = (bf*)smem;             // epilogue overlay [64][136] = 17408 B
    __shared__ float redS[4];

    const int t = threadIdx.x;
    const int flat = blockIdx.y * gridDim.x + blockIdx.x;
    const int lane8 = flat & 7;
    const int grp = flat >> 3;
    const int n_blk = grp % gridDim.x;
    const int m_blk = (grp / gridDim.x) * 8 + lane8;
    const int m0 = m_blk * 128, n0 = n_blk * 128;

    const int w = t >> 6, lane = t & 63;
    const int wm = (w >> 1) * 64, wn = (w & 1) * 64;
    const int fm = lane & 15;
    const int quad = lane >> 4;
    const int fk = quad * 8;
    const int srow = t >> 2, scol = (t & 3) * 8;

    f32x4 acc[4][4];
#pragma unroll
    for (int i = 0; i < 4; i++)
#pragma unroll
        for (int j = 0; j < 4; j++) acc[i][j] = (f32x4){0.f, 0.f, 0.f, 0.f};

    const int nk2 = K >> 6;
    for (int kt2 = 0; kt2 < nk2; kt2++) {
#pragma unroll
        for (int h = 0; h < 2; h++) {
            const int kt = kt2 * 2 + h;
            bf* Asg = (bf*)(smem + h * 16384);
            bf* Bsg = (bf*)(smem + h * 16384 + 8192);
            const bf* ga = A + (long)(m0 + srow) * K + kt * 32 + scol;
            const bf* gb = BT + (long)(n0 + srow) * K + kt * 32 + scol;
            async_copy16(ga, Asg + w * 512);
            async_copy16(ga + 64L * K, Asg + 2048 + w * 512);
            async_copy16(gb, Bsg + w * 512);
            async_copy16(gb + 64L * K, Bsg + 2048 + w * 512);
        }
        __syncthreads();

#pragma unroll
        for (int h = 0; h < 2; h++) {
            bf* Asg = (bf*)(smem + h * 16384);
            bf* Bsg = (bf*)(smem + h * 16384 + 8192);
            bf16x8 af[4], bfr[4];
#pragma unroll
            for (int mi = 0; mi < 4; mi++)
                af[mi] = *(const bf16x8*)&Asg[(wm + mi * 16 + fm) * 32 + fk];
#pragma unroll
            for (int ni = 0; ni < 4; ni++)
                bfr[ni] = *(const bf16x8*)&Bsg[(wn + ni * 16 + fm) * 32 + fk];
#pragma unroll
            for (int mi = 0; mi < 4; mi++)
#pragma unroll
                for (int ni = 0; ni < 4; ni++)
                    acc[mi][ni] = __builtin_amdgcn_mfma_f32_16x16x32_bf16(
                        af[mi], bfr[ni], acc[mi][ni], 0, 0, 0);
        }
        __syncthreads();
    }

    if (SQLOSS) {
        float lsum = 0.f;
#pragma unroll
        for (int ni = 0; ni < 4; ni++) {
            const int col = n0 + wn + ni * 16 + fm;
            const float b = bias[col];
#pragma unroll
            for (int mi = 0; mi < 4; mi++)
#pragma unroll
                for (int r = 0; r < 4; r++) {
                    const int row = m0 + wm + mi * 16 + quad * 4 + r;
                    const float x = fmaxf(acc[mi][ni][r] + b, 0.f);
                    const float d = x - Href[(long)(row / MC) * DIM + col];
                    lsum = fmaf(d, d, lsum);
                }
        }
        lsum = warpReduceSum(lsum);
        if (lane == 0) redS[w] = lsum;
        __syncthreads();
        if (t == 0) atomicAdd(lossAcc, redS[0] + redS[1] + redS[2] + redS[3]);
    } else {
        for (int hf = 0; hf < 2; hf++) {
            if ((w >> 1) == hf) {
#pragma unroll
                for (int ni = 0; ni < 4; ni++) {
                    const int c = wn + ni * 16 + fm;
                    const float bv = bias[n0 + c];
#pragma unroll
                    for (int mi = 0; mi < 4; mi++)
#pragma unroll
                        for (int r = 0; r < 4; r++) {
                            const float x = fmaxf(acc[mi][ni][r] + bv, 0.f);
                            Cs[(mi * 16 + quad * 4 + r) * 136 + c] = __float2bfloat16(x);
                        }
                }
            }
            __syncthreads();
            const int rl2 = t >> 2, cc2 = (t & 3) * 32;
            const long ob = (long)(m0 + hf * 64 + rl2) * N + n0 + cc2;
#pragma unroll
            for (int j = 0; j < 4; j++)
                *(bf16x8*)&C[ob + j * 8] = *(const bf16x8*)&Cs[rl2 * 136 + cc2 + j * 8];
            __syncthreads();
        }
    }
}

// ---------------------------------------------------------------------------
// one conversion kernel: scal zero + H split + ALL weights + EM buffer zero.
// grid 23447 x 256.
// ---------------------------------------------------------------------------
__global__ void conv_all(
    const float* __restrict__ H, bf* __restrict__ h0h, bf* __restrict__ h0l,
    const float* __restrict__ wq, const float* __restrict__ wk,
    const float* __restrict__ wv, const float* __restrict__ wo,
    bf* __restrict__ qkvTh0, bf* __restrict__ qkvTl0,
    bf* __restrict__ woTh0, bf* __restrict__ woTl0,
    bf* __restrict__ qkvTh1, bf* __restrict__ qkvTl1,
    bf* __restrict__ woTh1, bf* __restrict__ woTl1,
    const float* __restrict__ wz, bf* __restrict__ wzTh, bf* __restrict__ wzTl,
    const float* __restrict__ w1, bf* __restrict__ w1T,
    const float* __restrict__ w2, bf* __restrict__ w2T,
    const float* __restrict__ w3, bf* __restrict__ w3T,
    float* __restrict__ scal, float* __restrict__ msP, float* __restrict__ nkP)
{
    const int t = threadIdx.x;
    if (blockIdx.x == 0 && t < 16) scal[t] = 0.f;
    const int gidx = blockIdx.x * 256 + t;
    if (gidx < 2097152) {           // H -> split planes
        const float x = H[gidx];
        const bf h = __float2bfloat16(x);
        h0h[gidx] = h;
        h0l[gidx] = __float2bfloat16(x - __bfloat162float(h));
        return;
    }
    const int idx = gidx - 2097152;
    if (idx < 2097152) {            // MAB weights, both layers
        const int layer = idx >> 20;
        const int seg = (idx >> 18) & 3;
        const int r = idx & 262143;
        const int k = r >> 9, n = r & 511;
        const float* src = ((seg == 0) ? wq : (seg == 1) ? wk : (seg == 2) ? wv : wo)
                           + (long)layer * 262144;
        const float x = src[r];
        const bf h = __float2bfloat16(x);
        const bf l = __float2bfloat16(x - __bfloat162float(h));
        if (seg < 3) {
            const long o = (long)(seg * 512 + n) * 512 + k;
            if (layer == 0) { qkvTh0[o] = h; qkvTl0[o] = l; }
            else            { qkvTh1[o] = h; qkvTl1[o] = l; }
        } else {
            const long o = (long)n * 512 + k;
            if (layer == 0) { woTh0[o] = h; woTl0[o] = l; }
            else            { woTh1[o] = h; woTl1[o] = l; }
        }
    } else if (idx < 2162688) {     // wz: 512x128 split-T
        const int i = idx - 2097152;
        const int k = i >> 7, n = i & 127;
        const float x = wz[i];
        const bf h = __float2bfloat16(x);
        wzTh[(long)n * 512 + k] = h;
        wzTl[(long)n * 512 + k] = __float2bfloat16(x - __bfloat162float(h));
    } else if (idx < 2228224) {     // w1: 64x1024 plain-T
        const int i = idx - 2162688;
        const int k = i >> 10, n = i & 1023;
        w1T[(long)n * 64 + k] = __float2bfloat16(w1[i]);
    } else if (idx < 3276800) {     // w2: 1024x1024 plain-T
        const int i = idx - 2228224;
        const int k = i >> 10, n = i & 1023;
        w2T[(long)n * 1024 + k] = __float2bfloat16(w2[i]);
    } else if (idx < 3801088) {     // w3: 1024x512 plain-T
        const int i = idx - 3276800;
        const int k = i >> 9, n = i & 511;
        w3T[(long)n * 1024 + k] = __float2bfloat16(w3[i]);
    } else if (idx < 3903488) {     // zero EM musum buffers 1..5
        msP[20480 + (idx - 3801088)] = 0.f;
    } else if (idx < 3905088) {     // zero EM Nk buffers 1..5
        nkP[320 + (idx - 3903488)] = 0.f;
    }
}

// ---------------------------------------------------------------------------
__global__ __launch_bounds__(256)
void zgen(const float* __restrict__ stats, const float* __restrict__ eps,
          float* __restrict__ z, bf* __restrict__ z16)
{
    const int idx = blockIdx.x * 256 + threadIdx.x;
    const int bs = idx / 160;
    const int r = idx % 160;
    const int l4 = r % 16;
    const float4 e = ((const float4*)eps)[idx];
    const float4 mn = ((const float4*)stats)[bs * 32 + l4];
    const float4 lv = ((const float4*)stats)[bs * 32 + 16 + l4];
    float4 zz;
    zz.x = fmaf(e.x, expf(0.5f * lv.x), mn.x);
    zz.y = fmaf(e.y, expf(0.5f * lv.y), mn.y);
    zz.z = fmaf(e.z, expf(0.5f * lv.z), mn.z);
    zz.w = fmaf(e.w, expf(0.5f * lv.w), mn.w);
    ((float4*)z)[idx] = zz;
    bf* zp = z16 + (long)idx * 4;
    zp[0] = __float2bfloat16(zz.x);
    zp[1] = __float2bfloat16(zz.y);
    zp[2] = __float2bfloat16(zz.z);
    zp[3] = __float2bfloat16(zz.w);
}

// ---------------------------------------------------------------------------
__global__ void em_init(const float* __restrict__ z, const int* __restrict__ init_idx,
                        float* __restrict__ ms0, float* __restrict__ nk0)
{
    const int b = blockIdx.x, t = threadIdx.x;
    for (int i = t; i < KC * LD; i += 256) {
        const int k = i >> 6, l = i & 63;
        const int idx = init_idx[b * KC + k];
        ms0[b * KC * LD + i] = z[((long)b * NPTS + idx) * LD + l];
    }
    if (t < KC) nk0[b * KC + t] = 1.f;
}

// ---------------------------------------------------------------------------
__global__ __launch_bounds__(256)
void em_step(const float* __restrict__ z,
             const float* __restrict__ msIn, const float* __restrict__ nkIn,
             float* __restrict__ msOut, float* __restrict__ nkOut)
{
    __shared__ float muS[KC][65];
    __shared__ float m2lp[KC];
    __shared__ float NkU[KC];
    __shared__ float postS[KC][256];
    __shared__ float NkS[KC];

    const int tile = blockIdx.x, b = blockIdx.y, t = threadIdx.x;
    const int lane = t & 63, w = t >> 6;

    if (t < KC) NkU[t] = nkIn[b * KC + t];
    __syncthreads();
    for (int i = t; i < KC * LD; i += 256)
        muS[i >> 6][i & 63] = msIn[b * KC * LD + i] / NkU[i >> 6];
    __syncthreads();
    if (t < KC) {
        float s = 0.f;
        for (int l = 0; l < LD; l++) { const float m = muS[t][l]; s = fmaf(m, m, s); }
        float sn = 0.f;
        for (int k = 0; k < KC; k++) sn += NkU[k];
        m2lp[t] = -0.5f * s + logf(NkU[t] / sn);
    }
    __syncthreads();

    const long n = (long)tile * 256 + t;
    const float* zr = &z[((long)b * NPTS + n) * LD];
    float acc[KC];
#pragma unroll
    for (int k = 0; k < KC; k++) acc[k] = 0.f;
#pragma unroll
    for (int l4 = 0; l4 < 16; l4++) {
        const float4 zv = ((const float4*)zr)[l4];
#pragma unroll
        for (int k = 0; k < KC; k++) {
            acc[k] = fmaf(zv.x, muS[k][l4 * 4 + 0], acc[k]);
            acc[k] = fmaf(zv.y, muS[k][l4 * 4 + 1], acc[k]);
            acc[k] = fmaf(zv.z, muS[k][l4 * 4 + 2], acc[k]);
            acc[k] = fmaf(zv.w, muS[k][l4 * 4 + 3], acc[k]);
        }
    }
    float mx = -1e30f;
    float llv[KC];
#pragma unroll
    for (int k = 0; k < KC; k++) { llv[k] = acc[k] + m2lp[k]; mx = fmaxf(mx, llv[k]); }
    float s = 0.f;
#pragma unroll
    for (int k = 0; k < KC; k++) { llv[k] = expf(llv[k] - mx); s += llv[k]; }
    const float inv = 1.f / s;
#pragma unroll
    for (int k = 0; k < KC; k++) postS[k][t] = llv[k] * inv;
    __syncthreads();

#pragma unroll
    for (int kk = 0; kk < 5; kk++) {
        const int k = w * 5 + kk;
        float p = postS[k][lane] + postS[k][lane + 64] + postS[k][lane + 128] + postS[k][lane + 192];
        p = warpReduceSum(p);
        if (lane == 0) NkS[k] = p;
    }
    __syncthreads();

    const float* zb = &z[((long)b * NPTS + (long)tile * 256) * LD];
#pragma unroll
    for (int j = 0; j < 5; j++) {
        const int o = t + j * 256;
        const int k = o >> 6, l = o & 63;
        float sacc = 0.f;
        for (int n2 = 0; n2 < 256; n2++)
            sacc = fmaf(postS[k][n2], zb[n2 * LD + l], sacc);
        atomicAdd(&msOut[b * KC * LD + o], sacc);
    }
    if (t < KC) atomicAdd(&nkOut[b * KC + t], NkS[t]);
}

// ---------------------------------------------------------------------------
__global__ __launch_bounds__(256)
void kl_kernel(const float* __restrict__ z, const float* __restrict__ stats,
               const float* __restrict__ eps,
               const float* __restrict__ msIn, const float* __restrict__ nkIn,
               float* __restrict__ klAcc)
{
    __shared__ float muS[KC][65];
    __shared__ float m2lp[KC];
    __shared__ float NkU[KC];
    __shared__ float redS[4];

    const int tile = blockIdx.x, b = blockIdx.y, t = threadIdx.x;

    if (t < KC) NkU[t] = nkIn[b * KC + t];
    __syncthreads();
    for (int i = t; i < KC * LD; i += 256)
        muS[i >> 6][i & 63] = msIn[b * KC * LD + i] / NkU[i >> 6];
    __syncthreads();
    if (t < KC) {
        float s = 0.f;
        for (int l = 0; l < LD; l++) { const float m = muS[t][l]; s = fmaf(m, m, s); }
        float sn = 0.f;
        for (int k = 0; k < KC; k++) sn += NkU[k];
        m2lp[t] = -0.5f * s + logf(NkU[t] / sn);
    }
    __syncthreads();

    const int n = tile * 256 + t;
    const int sidx = n / MC, m = n % MC;
    const long bs = (long)b * SEQ + sidx;
    const float* zr = &z[((long)b * NPTS + n) * LD];

    float acc[KC];
#pragma unroll
    for (int k = 0; k < KC; k++) acc[k] = 0.f;
    float x2 = 0.f;
#pragma unroll
    for (int l4 = 0; l4 < 16; l4++) {
        const float4 zv = ((const float4*)zr)[l4];
        x2 = fmaf(zv.x, zv.x, fmaf(zv.y, zv.y, fmaf(zv.z, zv.z, fmaf(zv.w, zv.w, x2))));
#pragma unroll
        for (int k = 0; k < KC; k++) {
            acc[k] = fmaf(zv.x, muS[k][l4 * 4 + 0], acc[k]);
            acc[k] = fmaf(zv.y, muS[k][l4 * 4 + 1], acc[k]);
            acc[k] = fmaf(zv.z, muS[k][l4 * 4 + 2], acc[k]);
            acc[k] = fmaf(zv.w, muS[k][l4 * 4 + 3], acc[k]);
        }
    }
    float mx = -1e30f;
    float llv[KC];
#pragma unroll
    for (int k = 0; k < KC; k++) { llv[k] = acc[k] + m2lp[k]; mx = fmaxf(mx, llv[k]); }
    float s = 0.f;
#pragma unroll
    for (int k = 0; k < KC; k++) s += expf(llv[k] - mx);
    const float log_pz = -0.5f * x2 + mx + logf(s) + LD * LOG_NORM;

    const float* lvr = &stats[bs * 128 + 64];
    const float* er = &eps[(bs * MC + m) * LD];
    float slv = 0.f, se2 = 0.f;
#pragma unroll
    for (int l4 = 0; l4 < 16; l4++) {
        const float4 lv = ((const float4*)lvr)[l4];
        slv += lv.x + lv.y + lv.z + lv.w;
        const float4 e = ((const float4*)er)[l4];
        se2 = fmaf(e.x, e.x, fmaf(e.y, e.y, fmaf(e.z, e.z, fmaf(e.w, e.w, se2))));
    }
    const float log_qz = -0.5f * (slv + se2) + LD * LOG_NORM;

    float v = log_qz - log_pz;
    v = warpReduceSum(v);
    if ((t & 63) == 0) redS[t >> 6] = v;
    __syncthreads();
    if (t == 0) atomicAdd(klAcc, redS[0] + redS[1] + redS[2] + redS[3]);
}

__global__ void finalize(const float* __restrict__ scal, float* __restrict__ out)
{
    if (threadIdx.x == 0) {
        out[0] = scal[0] * (1.f / (float)NROWS);
        out[1] = scal[1] * (1.f / (float)NROWS);
    }
}

// ---------------------------------------------------------------------------
extern "C" void kernel_launch(void* const* d_in, const int* in_sizes, int n_in,
                              void* d_out, int out_size, void* d_ws, size_t ws_size,
                              hipStream_t stream)
{
    const float* H   = (const float*)d_in[0];
    const float* eps = (const float*)d_in[1];
    const float* wq  = (const float*)d_in[2];
    const float* bq  = (const float*)d_in[3];
    const float* wk  = (const float*)d_in[4];
    const float* bk  = (const float*)d_in[5];
    const float* wv  = (const float*)d_in[6];
    const float* bv  = (const float*)d_in[7];
    const float* wo  = (const float*)d_in[8];
    const float* bo  = (const float*)d_in[9];
    const float* wz  = (const float*)d_in[10];
    const float* bz  = (const float*)d_in[11];
    const float* w1  = (const float*)d_in[12];
    const float* b1  = (const float*)d_in[13];
    const float* w2  = (const float*)d_in[14];
    const float* b2  = (const float*)d_in[15];
    const float* w3  = (const float*)d_in[16];
    const float* b3  = (const float*)d_in[17];
    const int* init_idx = (const int*)d_in[18];
    float* out = (float*)d_out;
    float* wsf = (float*)d_ws;

    // ---- workspace layout (float slots), ws = 256 MiB, used ~240 MB ----
    const long o_scal  = 0;
    const long o_nk    = 1024;
    const long o_ms    = 4096;
    const long o_st    = 131072;
    const long o_zb    = 655360;
    const long o_z16   = 3276800;
    const long o_q     = 4587520;
    const long o_k     = 6684672;
    const long o_vT    = 8781824;
    const long o_o     = 10878976;
    const long o_h1    = 12976128;
    const long o_qkvT0 = 15073280;
    const long o_woT0  = 15859712;
    const long o_qkvT1 = 16121856;
    const long o_woT1  = 16908288;
    const long o_wzT   = 17170432;
    const long o_w1T   = 17235968;
    const long o_w2T   = 17268736;
    const long o_w3T   = 17793024;
    const long o_d1    = 18055168;
    const long o_d2    = 39026688;   // ends 59998208 (240 MB)

    const long PL = (long)BS_TOT * DIM;
    bf* qh  = (bf*)(wsf + o_q);   bf* ql  = qh + PL;
    bf* kh  = (bf*)(wsf + o_k);   bf* kl_ = kh + PL;
    bf* vTh = (bf*)(wsf + o_vT);  bf* vTl = vTh + PL;
    bf* oh  = (bf*)(wsf + o_o);   bf* ol  = oh + PL;
    bf* h1h = (bf*)(wsf + o_h1);  bf* h1l = h1h + PL;
    bf* h2h = qh;                 bf* h2l = ql;
    bf* qkvTh0 = (bf*)(wsf + o_qkvT0); bf* qkvTl0 = qkvTh0 + 1536L * 512;
    bf* woTh0  = (bf*)(wsf + o_woT0);  bf* woTl0  = woTh0 + 512L * 512;
    bf* qkvTh1 = (bf*)(wsf + o_qkvT1); bf* qkvTl1 = qkvTh1 + 1536L * 512;
    bf* woTh1  = (bf*)(wsf + o_woT1);  bf* woTl1  = woTh1 + 512L * 512;
    bf* wzTh = (bf*)(wsf + o_wzT);     bf* wzTl = wzTh + 128L * 512;
    bf* w1T = (bf*)(wsf + o_w1T);
    bf* w2T = (bf*)(wsf + o_w2T);
    bf* w3T = (bf*)(wsf + o_w3T);
    bf* z16 = (bf*)(wsf + o_z16);
    bf* d1  = (bf*)(wsf + o_d1);
    bf* d2  = (bf*)(wsf + o_d2);
    float* st = wsf + o_st;
    float* zb = wsf + o_zb;
    float* scal = wsf + o_scal;
    float* msP = wsf + o_ms;
    float* nkP = wsf + o_nk;

    const dim3 blk(256);

    // ---- all conversions + scal zero + EM buffer zero, one launch ----
    conv_all<<<23447, blk, 0, stream>>>(
        H, h1h, h1l,
        wq, wk, wv, wo,
        qkvTh0, qkvTl0, woTh0, woTl0,
        qkvTh1, qkvTl1, woTh1, woTl1,
        wz, wzTh, wzTl, w1, w1T, w2, w2T, w3, w3T,
        scal, msP, nkP);

    // ---- 2x MAB on split-bf16 MFMA ----
    for (int i = 0; i < 2; i++) {
        const long boff = (long)i * DIM;
        bf* qkh = i ? qkvTh1 : qkvTh0;  bf* qkl = i ? qkvTl1 : qkvTl0;
        bf* wh  = i ? woTh1 : woTh0;    bf* wl  = i ? woTl1 : woTl0;

        gemm3t<0><<<dim3(12, 64), blk, 0, stream>>>(
            h1h, h1l, qkh, qkl, 512, 512, 512,
            bq + boff, bk + boff, bv + boff, nullptr,
            qh, ql, kh, kl_, vTh, vTl, nullptr, nullptr);
        attn_fused<<<dim3(4, 64), blk, 0, stream>>>(qh, ql, kh, kl_, vTh, vTl, oh, ol);
        bf* houth = (i == 0) ? h1h : h2h;
        bf* houtl = (i == 0) ? h1l : h2l;
        gemm3t<3><<<dim3(4, 64), blk, 0, stream>>>(
            oh, ol, wh, wl, 512, 512, 512,
            bo + boff, nullptr, nullptr, nullptr,
            houth, houtl, nullptr, nullptr, nullptr, nullptr, oh, ol);
    }

    // ---- stats = h2 @ wz + bz ----
    gemm3t<4><<<dim3(1, 64), blk, 0, stream>>>(
        h2h, h2l, wzTh, wzTl, 512, 512, 512,
        bz, nullptr, nullptr, st,
        nullptr, nullptr, nullptr, nullptr, nullptr, nullptr, nullptr, nullptr);

    // ---- z (fp32 exact + bf16 copy) ----
    zgen<<<2560, blk, 0, stream>>>(st, eps, zb, z16);

    // ---- decoder MLP + fused rec_loss, single dispatch per layer ----
    gemm_mfma<false><<<dim3(8, 320), blk, 0, stream>>>(
        z16, w1T, d1, b1, nullptr, nullptr, 64, 1024);
    gemm_mfma<false><<<dim3(8, 320), blk, 0, stream>>>(
        d1, w2T, d2, b2, nullptr, nullptr, 1024, 1024);
    gemm_mfma<true><<<dim3(4, 320), blk, 0, stream>>>(
        d2, w3T, nullptr, b3, H, scal + 0, 1024, 512);

    // ---- EM: init buffer0, 5 ping-pong fused E+M steps, KL off buffer5 ----
    em_init<<<16, blk, 0, stream>>>(zb, init_idx, msP, nkP);
    for (int it = 0; it < 5; it++) {
        em_step<<<dim3(10, 16), blk, 0, stream>>>(
            zb,
            msP + (long)it * 16 * KC * LD, nkP + (long)it * 16 * KC,
            msP + (long)(it + 1) * 16 * KC * LD, nkP + (long)(it + 1) * 16 * KC);
    }
    kl_kernel<<<dim3(10, 16), blk, 0, stream>>>(
        zb, st, eps,
        msP + 5L * 16 * KC * LD, nkP + 5L * 16 * KC, scal + 1);

    finalize<<<1, 64, 0, stream>>>(scal, out);
}